// Round 15
// baseline (205.793 us; speedup 1.0000x reference)
//
#include <hip/hip_runtime.h>
#include <hip/hip_bf16.h>
#include <math.h>

#define B_      4
#define SD_     2048
#define SE_     2048
#define HIDIN   300
#define HIDMID  512
#define NH      8
#define DH      64
#define ESZ     ((size_t)4194304)          // elems per [32][2048][64] tensor
#define BUFB    24576                       // bytes per attn LDS buffer (Kh+Kl+V)

typedef __attribute__((ext_vector_type(8))) short          s16x8;
typedef __attribute__((ext_vector_type(8))) unsigned short u16x8;
typedef __attribute__((ext_vector_type(4))) unsigned short u16x4;
typedef __attribute__((ext_vector_type(4))) float          f32x4;

#define MFMA16 __builtin_amdgcn_mfma_f32_16x16x32_bf16

// logit scale: (1/sqrt(300)) * log2(e)  -> softmax done in base-2
#define QSCALE  0.0832940411f
#define NEGL   -1.4426950e9f               // -1e9 * log2e
#define DEFER_THR 24.0f                    // defer-max threshold (base-2 units)

__device__ __forceinline__ unsigned short f2bf(float f) {
    unsigned int u = __float_as_uint(f);
    u += 0x7fffu + ((u >> 16) & 1u);          // RNE
    return (unsigned short)(u >> 16);
}
__device__ __forceinline__ float bf2f(unsigned short s) {
    return __uint_as_float((unsigned int)s << 16);
}
__device__ __forceinline__ void gload16(const void* g, void* l) {
    __builtin_amdgcn_global_load_lds(
        (const __attribute__((address_space(1))) void*)g,
        (__attribute__((address_space(3))) void*)l, 16, 0, 0);
}
// Raw v_exp_f32 (no OCML denormal fixup): softmax-safe (underflow -> 0).
__device__ __forceinline__ float fexp2(float x) {
#if __has_builtin(__builtin_amdgcn_exp2f)
    return __builtin_amdgcn_exp2f(x);
#else
    return exp2f(x);
#endif
}

// ws ushort offsets
#define OF_QH   ((size_t)0)
#define OF_QL   (ESZ)
#define OF_KH   (2*ESZ)
#define OF_KL   (3*ESZ)
#define OF_VT   (4*ESZ)
#define OF_CA   (5*ESZ)                    // deH,deL,enH,enL (4 x 2621440)
#define OF_CW   (OF_CA + 10485760)         // WQh,WQl,WKh,WKl,WVh,WVl (6 x 163840)
#define OF_WOT  (OF_CW + 983040)           // 196608
#define OF_PART (OF_WOT + 196608)          // split-K partials: Opart 8388608 + ML 524288
#define WS_NEED_SPLIT ((size_t)(OF_PART + 8388608 + 524288) * 2)   // bytes

// ---------------------------------------------------------------------------
// Kernel 0: mask (int32) -> packed-bf16-pair bias table {0, NEGL} (pre-softmax
// additive: keeps running max masked-aware — required, see R12 NaN).
// addr(u32) = (((q>>4)*32 + tile)*4 + g)*128 + (q&15)*8, elem = sub*4+c.
// ---------------------------------------------------------------------------
__global__ __launch_bounds__(256) void bias_kernel(const int* __restrict__ mask,
                                                   unsigned int* __restrict__ BiasT)
{
    const int idx = blockIdx.x * 256 + threadIdx.x;    // 65536 threads
    const int q = idx >> 5, tile = idx & 31;
    const int* __restrict__ mrow = mask + (size_t)q * SE_ + tile * 64;
    const unsigned int NEGB = (unsigned int)f2bf(NEGL);
    const int qblk = q >> 4, qlo = q & 15;
#pragma unroll
    for (int g = 0; g < 4; ++g) {
        unsigned int w[8];
#pragma unroll
        for (int sub = 0; sub < 4; ++sub) {
            const int4 mm = *(const int4*)(mrow + sub * 16 + g * 4);
            w[sub * 2]     = (mm.x ? NEGB : 0u) | ((mm.y ? NEGB : 0u) << 16);
            w[sub * 2 + 1] = (mm.z ? NEGB : 0u) | ((mm.w ? NEGB : 0u) << 16);
        }
        unsigned int* dst = BiasT +
            ((((size_t)qblk * 32 + tile) * 4 + g) * 16 + qlo) * 8;
        *(uint4*)dst       = make_uint4(w[0], w[1], w[2], w[3]);
        *(uint4*)(dst + 4) = make_uint4(w[4], w[5], w[6], w[7]);
    }
}

// ---------------------------------------------------------------------------
// Kernel 1a: de/en fp32 -> split bf16 hi/lo, tiled GEMM-A layout.
// ---------------------------------------------------------------------------
__global__ __launch_bounds__(256) void convA_kernel(
    const float* __restrict__ de, const float* __restrict__ en,
    unsigned short* __restrict__ CA)
{
    const int idx = blockIdx.x * 256 + threadIdx.x;    // 81920 per matrix
    const int mat = blockIdx.y;
    const float* __restrict__ A = mat ? en : de;
    unsigned short* __restrict__ H = CA + (size_t)mat * 5242880;
    unsigned short* __restrict__ L = H + 2621440;
    const int row = idx / 10, ch = idx - row * 10;
    float v[32];
    if (ch < 9) {
#pragma unroll
        for (int i = 0; i < 8; ++i) {
            const float4 f = *(const float4*)(A + (size_t)row * 300 + ch * 32 + i * 4);
            v[i*4+0] = f.x; v[i*4+1] = f.y; v[i*4+2] = f.z; v[i*4+3] = f.w;
        }
    } else {
#pragma unroll
        for (int i = 0; i < 32; ++i) {
            const int k = 288 + i;
            v[i] = (k < 300) ? A[(size_t)row * 300 + k] : 0.f;
        }
    }
    const int r128 = row & 127;
    const int xr = (r128 >> 1) & 3;
    const size_t tb = ((size_t)(row >> 7) * 10 + ch) * 4096 + r128 * 32;
#pragma unroll
    for (int sub = 0; sub < 4; ++sub) {
        const int slot = sub ^ xr;
        u16x8 hv, lv;
#pragma unroll
        for (int e = 0; e < 8; ++e) {
            const float f = v[sub * 8 + e];
            const unsigned short h = f2bf(f);
            hv[e] = h; lv[e] = f2bf(f - bf2f(h));
        }
        *(u16x8*)(H + tb + slot * 8) = hv;
        *(u16x8*)(L + tb + slot * 8) = lv;
    }
}

// ---------------------------------------------------------------------------
// Kernel 1b: WQ/WK -> split bf16 hi/lo transposed tiled (QSCALE folded into
// WQ); WV hi only; WO -> plain bf16 transposed tiled (n padded 300->384).
// ---------------------------------------------------------------------------
__global__ __launch_bounds__(256) void convW_kernel(
    const float* __restrict__ WQ, const float* __restrict__ WK,
    const float* __restrict__ WV, const float* __restrict__ WO,
    unsigned short* __restrict__ CW, unsigned short* __restrict__ WOT)
{
    const int idx = blockIdx.x * 256 + threadIdx.x;
    if (idx < 122880) {                       // QKV: which x k(320) x n4(128)
        const int which = idx / 40960;
        const int rem = idx - which * 40960;
        const int k = rem >> 7;
        const int n0 = (rem & 127) * 4;
        const float* __restrict__ W = which == 0 ? WQ : (which == 1 ? WK : WV);
        unsigned short* __restrict__ H = CW + (size_t)which * 327680;
        unsigned short* __restrict__ L = H + 163840;
        const float sc = (which == 0) ? QSCALE : 1.f;
        float4 w = make_float4(0.f, 0.f, 0.f, 0.f);
        if (k < 300) w = *(const float4*)(W + (size_t)k * 512 + n0);
        const float wv4[4] = {w.x * sc, w.y * sc, w.z * sc, w.w * sc};
        const int ch = k >> 5, kk = k & 31;
#pragma unroll
        for (int j = 0; j < 4; ++j) {
            const int n = n0 + j, ntile = n >> 7, nr = n & 127;
            const size_t o = ((size_t)(ntile * 10 + ch) * 128 + nr) * 32
                           + (((kk >> 3) ^ ((nr >> 1) & 3)) << 3) + (kk & 7);
            const unsigned short h = f2bf(wv4[j]);
            H[o] = h;
            if (which < 2) L[o] = f2bf(wv4[j] - bf2f(h));
        }
    } else {                                   // WO: k(512) x n4(96)
        const int idx2 = idx - 122880;
        const int k = idx2 / 96, n4 = idx2 - k * 96;
        const int n0 = n4 * 4;
        float4 w = make_float4(0.f, 0.f, 0.f, 0.f);
        if (n0 < 300) w = *(const float4*)(WO + (size_t)k * 300 + n0);
        const float wv4[4] = {w.x, w.y, w.z, w.w};
        const int ch = k >> 5, kk = k & 31;
#pragma unroll
        for (int j = 0; j < 4; ++j) {
            const int n = n0 + j, ntile = n >> 7, nr = n & 127;
            const size_t o = ((size_t)(ntile * 16 + ch) * 128 + nr) * 32
                           + (((kk >> 3) ^ ((nr >> 1) & 3)) << 3) + (kk & 7);
            WOT[o] = f2bf(wv4[j]);
        }
    }
}

// ---------------------------------------------------------------------------
// Kernel 2a: MFMA Q/K projection (3-term). 512 blocks = 2/CU.
// ---------------------------------------------------------------------------
__global__ __launch_bounds__(256) void proj_qk_kernel(
    const unsigned short* __restrict__ CA, const unsigned short* __restrict__ CW,
    unsigned short* __restrict__ Qh, unsigned short* __restrict__ Ql,
    unsigned short* __restrict__ KhT, unsigned short* __restrict__ KlT)
{
    const int lin = blockIdx.x;
    const int which = lin >> 8;                        // 0=Q, 1=K
    const int t = lin & 255;
    const int stile = (t & 7) | ((t >> 5) << 3);
    const int jtile = (t >> 3) & 3;
    const int tid = threadIdx.x, wv = tid >> 6, lane = tid & 63;
    const int li = lane & 15, g = lane >> 4;
    const int wr = wv >> 1, wc = wv & 1;

    __shared__ __align__(16) char LBp[65536];

    const unsigned short* __restrict__ pAh =
        CA + (size_t)which * 5242880 + (size_t)stile * 40960 + tid * 8;
    const unsigned short* __restrict__ pAl = pAh + 2621440;
    const unsigned short* __restrict__ pWh =
        CW + (size_t)which * 327680 + (size_t)jtile * 40960 + tid * 8;
    const unsigned short* __restrict__ pWl = pWh + 163840;

#define STAGEP(ch, bofs) {                                                    \
        char* db = LBp + (bofs) + wv * 1024;                                  \
        const size_t co = (size_t)(ch) * 4096;                                \
        gload16(pAh + co,        db);                                         \
        gload16(pAh + co + 2048, db + 4096);                                  \
        gload16(pAl + co,        db + 8192);                                  \
        gload16(pAl + co + 2048, db + 12288);                                 \
        gload16(pWh + co,        db + 16384);                                 \
        gload16(pWh + co + 2048, db + 20480);                                 \
        gload16(pWl + co,        db + 24576);                                 \
        gload16(pWl + co + 2048, db + 28672);                                 \
    }

    int offA[4], offW[4];
#pragma unroll
    for (int ssub = 0; ssub < 4; ++ssub) {
        const int r = wr * 64 + ssub * 16 + li;
        offA[ssub] = r * 64 + ((g ^ ((r >> 1) & 3)) << 4);
    }
#pragma unroll
    for (int jsub = 0; jsub < 4; ++jsub) {
        const int n = wc * 64 + jsub * 16 + li;
        offW[jsub] = n * 64 + ((g ^ ((n >> 1) & 3)) << 4);
    }

    f32x4 acc[4][4];
#pragma unroll
    for (int i = 0; i < 4; ++i)
#pragma unroll
        for (int j = 0; j < 4; ++j) acc[i][j] = (f32x4){0.f, 0.f, 0.f, 0.f};

    STAGEP(0, 0)
    __syncthreads();

#pragma unroll 1
    for (int ch = 0; ch < 10; ++ch) {
        const int bofs = (ch & 1) * 32768;
        if (ch < 9) STAGEP(ch + 1, bofs ^ 32768)
        const char* bp = LBp + bofs;
        s16x8 ah[4], al[4], wh[4], wl[4];
#pragma unroll
        for (int ssub = 0; ssub < 4; ++ssub) {
            ah[ssub] = *(const s16x8*)(bp + offA[ssub]);
            al[ssub] = *(const s16x8*)(bp + 8192 + offA[ssub]);
        }
#pragma unroll
        for (int jsub = 0; jsub < 4; ++jsub) {
            wh[jsub] = *(const s16x8*)(bp + 16384 + offW[jsub]);
            wl[jsub] = *(const s16x8*)(bp + 24576 + offW[jsub]);
        }
        __builtin_amdgcn_s_setprio(1);
#pragma unroll
        for (int ssub = 0; ssub < 4; ++ssub)
#pragma unroll
            for (int jsub = 0; jsub < 4; ++jsub) {
                acc[ssub][jsub] = MFMA16(ah[ssub], wh[jsub], acc[ssub][jsub], 0, 0, 0);
                acc[ssub][jsub] = MFMA16(ah[ssub], wl[jsub], acc[ssub][jsub], 0, 0, 0);
                acc[ssub][jsub] = MFMA16(al[ssub], wh[jsub], acc[ssub][jsub], 0, 0, 0);
            }
        __builtin_amdgcn_s_setprio(0);
        __syncthreads();
    }
#undef STAGEP

    const int jgbase = jtile * 128 + wc * 64 + li;
    const int sbase0 = stile * 128 + wr * 64 + 4 * g;
#pragma unroll
    for (int jsub = 0; jsub < 4; ++jsub) {
        const int jgg = jgbase + jsub * 16;
        const int d = jgg >> 3, hh = jgg & 7;
#pragma unroll
        for (int ssub = 0; ssub < 4; ++ssub) {
            const f32x4 v = acc[ssub][jsub];
            const int sg0 = sbase0 + ssub * 16;
            const int bbv = sg0 >> 11;
            const int bhn = bbv * 8 + hh;
            const int sl0 = sg0 & 2047;
            if (which == 0) {
                const size_t o = ((size_t)bhn * 2048 + sl0) * 64 + d;
#pragma unroll
                for (int r = 0; r < 4; ++r) {
                    const float val = v[r];
                    const unsigned short hi = f2bf(val);
                    Qh[o + r * 64] = hi;
                    Ql[o + r * 64] = f2bf(val - bf2f(hi));
                }
            } else {
                const int tile = sl0 >> 6, tt0 = sl0 & 63;
                const size_t tb = ((size_t)(bhn * 32 + tile)) << 12;
#pragma unroll
                for (int r = 0; r < 4; ++r) {
                    const int tt = tt0 + r;
                    const size_t o = tb + tt * 64 + (((d >> 3) ^ (tt & 7)) << 3) + (d & 7);
                    const float val = v[r];
                    const unsigned short hi = f2bf(val);
                    KhT[o] = hi;
                    KlT[o] = f2bf(val - bf2f(hi));
                }
            }
        }
    }
}

// ---------------------------------------------------------------------------
// Kernel 2b: MFMA V projection (1-term). 256 blocks, 32 KB LDS.
// ---------------------------------------------------------------------------
__global__ __launch_bounds__(256) void proj_v_kernel(
    const unsigned short* __restrict__ CA, const unsigned short* __restrict__ CW,
    unsigned short* __restrict__ VtT)
{
    const int t = blockIdx.x;
    const int stile = (t & 7) | ((t >> 5) << 3);
    const int jtile = (t >> 3) & 3;
    const int tid = threadIdx.x, wv = tid >> 6, lane = tid & 63;
    const int li = lane & 15, g = lane >> 4;
    const int wr = wv >> 1, wc = wv & 1;

    __shared__ __align__(16) char LBv[32768];

    const unsigned short* __restrict__ pAh =
        CA + (size_t)1 * 5242880 + (size_t)stile * 40960 + tid * 8;
    const unsigned short* __restrict__ pWh =
        CW + (size_t)2 * 327680 + (size_t)jtile * 40960 + tid * 8;

#define STAGEV(ch, bofs) {                                                    \
        char* db = LBv + (bofs) + wv * 1024;                                  \
        const size_t co = (size_t)(ch) * 4096;                                \
        gload16(pAh + co,        db);                                         \
        gload16(pAh + co + 2048, db + 4096);                                  \
        gload16(pWh + co,        db + 8192);                                  \
        gload16(pWh + co + 2048, db + 12288);                                 \
    }

    int offA[4], offW[4];
#pragma unroll
    for (int ssub = 0; ssub < 4; ++ssub) {
        const int r = wr * 64 + ssub * 16 + li;
        offA[ssub] = r * 64 + ((g ^ ((r >> 1) & 3)) << 4);
    }
#pragma unroll
    for (int jsub = 0; jsub < 4; ++jsub) {
        const int n = wc * 64 + jsub * 16 + li;
        offW[jsub] = 8192 + n * 64 + ((g ^ ((n >> 1) & 3)) << 4);
    }

    f32x4 acc[4][4];
#pragma unroll
    for (int i = 0; i < 4; ++i)
#pragma unroll
        for (int j = 0; j < 4; ++j) acc[i][j] = (f32x4){0.f, 0.f, 0.f, 0.f};

    STAGEV(0, 0)
    __syncthreads();

#pragma unroll 1
    for (int ch = 0; ch < 10; ++ch) {
        const int bofs = (ch & 1) * 16384;
        if (ch < 9) STAGEV(ch + 1, bofs ^ 16384)
        const char* bp = LBv + bofs;
        s16x8 ah[4], wh[4];
#pragma unroll
        for (int ssub = 0; ssub < 4; ++ssub)
            ah[ssub] = *(const s16x8*)(bp + offA[ssub]);
#pragma unroll
        for (int jsub = 0; jsub < 4; ++jsub)
            wh[jsub] = *(const s16x8*)(bp + offW[jsub]);
        __builtin_amdgcn_s_setprio(1);
#pragma unroll
        for (int ssub = 0; ssub < 4; ++ssub)
#pragma unroll
            for (int jsub = 0; jsub < 4; ++jsub)
                acc[ssub][jsub] = MFMA16(ah[ssub], wh[jsub], acc[ssub][jsub], 0, 0, 0);
        __builtin_amdgcn_s_setprio(0);
        __syncthreads();
    }
#undef STAGEV

    const int jgbase = jtile * 128 + wc * 64 + li;
    const int sbase0 = stile * 128 + wr * 64 + 4 * g;
#pragma unroll
    for (int jsub = 0; jsub < 4; ++jsub) {
        const int jgg = jgbase + jsub * 16;
        const int d = jgg >> 3, hh = jgg & 7;
#pragma unroll
        for (int ssub = 0; ssub < 4; ++ssub) {
            const f32x4 v = acc[ssub][jsub];
            const int sg0 = sbase0 + ssub * 16;
            const int bbv = sg0 >> 11;
            const int bhn = bbv * 8 + hh;
            const int sl0 = sg0 & 2047;
            const int tile = sl0 >> 6, tin0 = sl0 & 63;
            const size_t tb = ((size_t)(bhn * 32 + tile)) << 12;
            const int blk = tin0 >> 5, gg2 = (tin0 >> 2) & 3, half = (tin0 >> 4) & 1;
            const size_t o = tb + (size_t)d * 64
                           + ((((blk << 2) | gg2) ^ (d & 7)) << 3) + half * 4;
            u16x4 pk;
#pragma unroll
            for (int r = 0; r < 4; ++r) pk[r] = f2bf(v[r]);
            *(u16x4*)(VtT + o) = pk;
        }
    }
}

// ---------------------------------------------------------------------------
// Kernel 3 (fallback, R14-verified): MFMA flash attention, 16 q/wave.
// ---------------------------------------------------------------------------
__global__ __launch_bounds__(512, 4) void attn_mfma_kernel(
    const unsigned short* __restrict__ Qh, const unsigned short* __restrict__ Ql,
    const unsigned short* __restrict__ KhT, const unsigned short* __restrict__ KlT,
    const unsigned short* __restrict__ VtT, const unsigned int* __restrict__ BiasT,
    unsigned short* __restrict__ AOb)
{
    const int lin = blockIdx.x + 16 * blockIdx.y;
    const int qt = (lin >> 3) & 15;
    const int bh = (lin & 7) + ((lin >> 7) << 3);
    const int bb = bh >> 3, hh = bh & 7;
    const int tid = threadIdx.x;
    const int wv = tid >> 6, lane = tid & 63;
    const int g = lane >> 4, li = lane & 15;
    const int q = qt * 128 + wv * 16 + li;

    __shared__ __align__(16) char LB[3 * BUFB];

    const size_t qoff = ((size_t)bh * SD_ + q) * DH + 8 * g;
    const s16x8 qh0 = *(const s16x8*)(Qh + qoff);
    const s16x8 qh1 = *(const s16x8*)(Qh + qoff + 32);
    const s16x8 ql0 = *(const s16x8*)(Ql + qoff);
    const s16x8 ql1 = *(const s16x8*)(Ql + qoff + 32);

    const unsigned short* __restrict__ sKh = KhT + ((size_t)bh << 17) + tid * 8;
    const unsigned short* __restrict__ sKl = KlT + ((size_t)bh << 17) + tid * 8;
    const unsigned short* __restrict__ sVt = VtT + ((size_t)bh << 17) + tid * 8;

    const int base0 = li * 128 + ((g ^ (li & 7)) << 4);
    const int base1 = li * 128 + (((4 + g) ^ (li & 7)) << 4);

    const size_t bbase = (size_t)(qt * 8 + wv) * 16384 + g * 128 + li * 8;

#define BIASLOAD(T, RA, RB) {                                                 \
        const uint4* p = (const uint4*)(BiasT + bbase + (size_t)(T) * 512);   \
        RA = p[0]; RB = p[1];                                                 \
    }
#define STAGE(tile, boff)                                                     \
    {                                                                         \
        char* db = LB + (boff) + wv * 1024;                                   \
        const size_t toff = (size_t)(tile) << 12;                             \
        gload16(sKh + toff, db);                                              \
        gload16(sKl + toff, db + 8192);                                       \
        gload16(sVt + toff, db + 16384);                                      \
    }

    float m = -INFINITY;
    f32x4 O[4], lacc;
#pragma unroll
    for (int i = 0; i < 4; ++i) O[i] = (f32x4){0.f, 0.f, 0.f, 0.f};
    lacc = (f32x4){0.f, 0.f, 0.f, 0.f};

    s16x8 ones;
#pragma unroll
    for (int i = 0; i < 8; ++i) ones[i] = (short)0x3F80;

    uint4 cBA, cBB, nBA, nBB;

#define UNPK(W, S, sub, cbase)                                                \
        S[sub][cbase]     = __uint_as_float((W) << 16);                       \
        S[sub][cbase + 1] = __uint_as_float((W) & 0xFFFF0000u);

#define ITER(IT, CBA_, CBB_, NBA_, NBB_)                                      \
    {                                                                         \
        BIASLOAD(((IT) + 1) & 31, NBA_, NBB_)                                 \
        STAGE(((IT) + 2) & 31, cs)                                            \
        f32x4 s[4];                                                           \
        UNPK(CBA_.x, s, 0, 0) UNPK(CBA_.y, s, 0, 2)                           \
        UNPK(CBA_.z, s, 1, 0) UNPK(CBA_.w, s, 1, 2)                           \
        UNPK(CBB_.x, s, 2, 0) UNPK(CBB_.y, s, 2, 2)                           \
        UNPK(CBB_.z, s, 3, 0) UNPK(CBB_.w, s, 3, 2)                           \
        __builtin_amdgcn_s_setprio(1);                                        \
        _Pragma("unroll")                                                     \
        for (int sub = 0; sub < 4; ++sub) {                                   \
            const s16x8 kh0 = *(const s16x8*)(LB + cc + base0 + sub * 2048);  \
            const s16x8 kh1 = *(const s16x8*)(LB + cc + base1 + sub * 2048);  \
            const s16x8 kl0 = *(const s16x8*)(LB + cc + base0 + 8192 + sub * 2048); \
            const s16x8 kl1 = *(const s16x8*)(LB + cc + base1 + 8192 + sub * 2048); \
            s[sub] = MFMA16(kh0, qh0, s[sub], 0, 0, 0);                       \
            s[sub] = MFMA16(kh0, ql0, s[sub], 0, 0, 0);                       \
            s[sub] = MFMA16(kl0, qh0, s[sub], 0, 0, 0);                       \
            s[sub] = MFMA16(kh1, qh1, s[sub], 0, 0, 0);                       \
            s[sub] = MFMA16(kh1, ql1, s[sub], 0, 0, 0);                       \
            s[sub] = MFMA16(kl1, qh1, s[sub], 0, 0, 0);                       \
        }                                                                     \
        __builtin_amdgcn_s_setprio(0);                                        \
        float x0 = fmaxf(fmaxf(s[0][0], s[0][1]), s[0][2]);                   \
        float x1 = fmaxf(fmaxf(s[0][3], s[1][0]), s[1][1]);                   \
        float x2 = fmaxf(fmaxf(s[1][2], s[1][3]), s[2][0]);                   \
        float x3 = fmaxf(fmaxf(s[2][1], s[2][2]), s[2][3]);                   \
        float x4 = fmaxf(fmaxf(s[3][0], s[3][1]), s[3][2]);                   \
        float tmax = fmaxf(fmaxf(fmaxf(x0, x1), fmaxf(x2, x3)),               \
                           fmaxf(x4, s[3][3]));                               \
        if (!__all(tmax <= m + DEFER_THR)) {                                  \
            float r = fmaxf(tmax, __shfl_xor(tmax, 16));                      \
            r = fmaxf(r, __shfl_xor(r, 32));                                  \
            const float mn  = fmaxf(m, r);                                    \
            const float scl = fexp2(m - mn);                                  \
            m = mn;                                                           \
            _Pragma("unroll")                                                 \
            for (int i = 0; i < 4; ++i) O[i] *= scl;                          \
            lacc *= scl;                                                      \
        }                                                                     \
        _Pragma("unroll")                                                     \
        for (int sub = 0; sub < 4; ++sub)                                     \
            _Pragma("unroll")                                                 \
            for (int c = 0; c < 4; ++c)                                       \
                s[sub][c] = fexp2(s[sub][c] - m);                             \
        union { s16x8 v; unsigned int w[4]; } P0, P1;                         \
        asm("v_cvt_pk_bf16_f32 %0, %1, %2" : "=v"(P0.w[0]) : "v"(s[0][0]), "v"(s[0][1])); \
        asm("v_cvt_pk_bf16_f32 %0, %1, %2" : "=v"(P0.w[1]) : "v"(s[0][2]), "v"(s[0][3])); \
        asm("v_cvt_pk_bf16_f32 %0, %1, %2" : "=v"(P0.w[2]) : "v"(s[1][0]), "v"(s[1][1])); \
        asm("v_cvt_pk_bf16_f32 %0, %1, %2" : "=v"(P0.w[3]) : "v"(s[1][2]), "v"(s[1][3])); \
        asm("v_cvt_pk_bf16_f32 %0, %1, %2" : "=v"(P1.w[0]) : "v"(s[2][0]), "v"(s[2][1])); \
        asm("v_cvt_pk_bf16_f32 %0, %1, %2" : "=v"(P1.w[1]) : "v"(s[2][2]), "v"(s[2][3])); \
        asm("v_cvt_pk_bf16_f32 %0, %1, %2" : "=v"(P1.w[2]) : "v"(s[3][0]), "v"(s[3][1])); \
        asm("v_cvt_pk_bf16_f32 %0, %1, %2" : "=v"(P1.w[3]) : "v"(s[3][2]), "v"(s[3][3])); \
        __builtin_amdgcn_s_setprio(1);                                        \
        _Pragma("unroll")                                                     \
        for (int dsub = 0; dsub < 4; ++dsub) {                                \
            const s16x8 vf0 = *(const s16x8*)(LB + cc + base0 + 16384 + dsub * 2048); \
            const s16x8 vf1 = *(const s16x8*)(LB + cc + base1 + 16384 + dsub * 2048); \
            O[dsub] = MFMA16(vf0, P0.v, O[dsub], 0, 0, 0);                    \
            O[dsub] = MFMA16(vf1, P1.v, O[dsub], 0, 0, 0);                    \
        }                                                                     \
        lacc = MFMA16(ones, P0.v, lacc, 0, 0, 0);                             \
        lacc = MFMA16(ones, P1.v, lacc, 0, 0, 0);                             \
        __builtin_amdgcn_s_setprio(0);                                        \
        asm volatile("s_waitcnt vmcnt(3)" ::: "memory");                      \
        __builtin_amdgcn_s_barrier();                                         \
        __builtin_amdgcn_sched_barrier(0);                                    \
        cc += BUFB; if (cc == 3 * BUFB) cc = 0;                               \
        cs += BUFB; if (cs == 3 * BUFB) cs = 0;                               \
    }

    int cc = 0, cs = 2 * BUFB;

    BIASLOAD(0, cBA, cBB)
    STAGE(0, 0)
    STAGE(1, BUFB)
    asm volatile("s_waitcnt vmcnt(3)" ::: "memory");
    __builtin_amdgcn_s_barrier();
    __builtin_amdgcn_sched_barrier(0);

#pragma unroll 1
    for (int it = 0; it < 32; it += 2) {
        ITER(it,     cBA, cBB, nBA, nBB)
        ITER(it + 1, nBA, nBB, cBA, cBB)
    }

    const float rl = 1.f / lacc[0];
    const int row = bb * 2048 + q;
    const int r128 = row & 127;
    const int xr = (r128 >> 1) & 3;
    unsigned short* __restrict__ ab = AOb + ((size_t)(row >> 7)) * 65536
                                    + r128 * 32 + (g & 1) * 4;
#pragma unroll
    for (int dsub = 0; dsub < 4; ++dsub) {
        const f32x4 o = O[dsub] * rl;
        const int ch = hh * 2 + (dsub >> 1);
        const int slot = ((dsub & 1) * 2 + (g >> 1)) ^ xr;
        u16x4 pk;
#pragma unroll
        for (int c = 0; c < 4; ++c) pk[c] = f2bf(o[c]);
        *(u16x4*)(ab + (size_t)ch * 4096 + slot * 8) = pk;
    }
#undef STAGE
#undef BIASLOAD
#undef UNPK
#undef ITER
}

// ---------------------------------------------------------------------------
// Kernel 3b: split-K 2-qset attention. 512 blocks = 8 qt x 32 bh x 2 splits,
// 8 waves x 32 q-rows (2 q-sets/wave). K/V LDS reads amortized 2x. Emits
// unnormalized bf16 O-partials + (m,l) per row; merged by merge_kernel.
// ---------------------------------------------------------------------------
__global__ __launch_bounds__(512, 4) void attn2_kernel(
    const unsigned short* __restrict__ Qh, const unsigned short* __restrict__ Ql,
    const unsigned short* __restrict__ KhT, const unsigned short* __restrict__ KlT,
    const unsigned short* __restrict__ VtT, const unsigned int* __restrict__ BiasT,
    unsigned short* __restrict__ Opart, float2* __restrict__ ML)
{
    const int lin = blockIdx.x + 16 * blockIdx.y;
    const int qt2 = (lin >> 3) & 15;
    const int qt = qt2 >> 1, split = qt2 & 1;
    const int bh = (lin & 7) | ((lin >> 7) << 3);
    const int tid = threadIdx.x;
    const int wv = tid >> 6, lane = tid & 63;
    const int g = lane >> 4, li = lane & 15;
    const int q0 = qt * 256 + wv * 16 + li;            // qset0; qset1 = +128
    const int tbase = split * 16;

    __shared__ __align__(16) char LB[3 * BUFB];

    const size_t qoff = ((size_t)bh * SD_ + q0) * DH + 8 * g;
    const s16x8 qh0_0 = *(const s16x8*)(Qh + qoff);
    const s16x8 qh1_0 = *(const s16x8*)(Qh + qoff + 32);
    const s16x8 ql0_0 = *(const s16x8*)(Ql + qoff);
    const s16x8 ql1_0 = *(const s16x8*)(Ql + qoff + 32);
    const s16x8 qh0_1 = *(const s16x8*)(Qh + qoff + 8192);
    const s16x8 qh1_1 = *(const s16x8*)(Qh + qoff + 8224);
    const s16x8 ql0_1 = *(const s16x8*)(Ql + qoff + 8192);
    const s16x8 ql1_1 = *(const s16x8*)(Ql + qoff + 8224);

    const unsigned short* __restrict__ sKh = KhT + ((size_t)bh << 17) + tid * 8;
    const unsigned short* __restrict__ sKl = KlT + ((size_t)bh << 17) + tid * 8;
    const unsigned short* __restrict__ sVt = VtT + ((size_t)bh << 17) + tid * 8;

    const int base0 = li * 128 + ((g ^ (li & 7)) << 4);
    const int base1 = li * 128 + (((4 + g) ^ (li & 7)) << 4);

    const size_t bb0 = (size_t)(qt * 16 + wv) * 16384 + g * 128 + li * 8;
    const size_t bb1 = bb0 + 131072;                   // +8 q16-groups

#define STAGE2(tile, boff)                                                    \
    {                                                                         \
        char* db = LB + (boff) + wv * 1024;                                   \
        const size_t toff = (size_t)(tile) << 12;                             \
        gload16(sKh + toff, db);                                              \
        gload16(sKl + toff, db + 8192);                                       \
        gload16(sVt + toff, db + 16384);                                      \
    }
#define UNPK2(W, S, sub, cbase)                                               \
        S[sub][cbase]     = __uint_as_float((W) << 16);                       \
        S[sub][cbase + 1] = __uint_as_float((W) & 0xFFFF0000u);

    float m0 = -INFINITY, m1 = -INFINITY;
    f32x4 O0[4], O1[4], lacc0, lacc1;
#pragma unroll
    for (int i = 0; i < 4; ++i) {
        O0[i] = (f32x4){0.f, 0.f, 0.f, 0.f};
        O1[i] = (f32x4){0.f, 0.f, 0.f, 0.f};
    }
    lacc0 = (f32x4){0.f, 0.f, 0.f, 0.f};
    lacc1 = (f32x4){0.f, 0.f, 0.f, 0.f};

    s16x8 ones;
#pragma unroll
    for (int i = 0; i < 8; ++i) ones[i] = (short)0x3F80;

    int cc = 0, cs = 2 * BUFB;
    STAGE2(tbase, 0)
    STAGE2(tbase + 1, BUFB)
    asm volatile("s_waitcnt vmcnt(3)" ::: "memory");
    __builtin_amdgcn_s_barrier();
    __builtin_amdgcn_sched_barrier(0);

#pragma unroll 1
    for (int it = 0; it < 16; ++it) {
        // bias for current tile, both qsets (in-iter; latency hidden by S-MFMAs
        // of the consuming sub-chains + co-resident waves)
        const uint4* pb0 = (const uint4*)(BiasT + bb0 + (size_t)(tbase + it) * 512);
        const uint4 bA0 = pb0[0], bB0 = pb0[1];
        const uint4* pb1 = (const uint4*)(BiasT + bb1 + (size_t)(tbase + it) * 512);
        const uint4 bA1 = pb1[0], bB1 = pb1[1];
        STAGE2(tbase + ((it + 2) & 15), cs)

        f32x4 s0[4], s1[4];
        UNPK2(bA0.x, s0, 0, 0) UNPK2(bA0.y, s0, 0, 2)
        UNPK2(bA0.z, s0, 1, 0) UNPK2(bA0.w, s0, 1, 2)
        UNPK2(bB0.x, s0, 2, 0) UNPK2(bB0.y, s0, 2, 2)
        UNPK2(bB0.z, s0, 3, 0) UNPK2(bB0.w, s0, 3, 2)
        UNPK2(bA1.x, s1, 0, 0) UNPK2(bA1.y, s1, 0, 2)
        UNPK2(bA1.z, s1, 1, 0) UNPK2(bA1.w, s1, 1, 2)
        UNPK2(bB1.x, s1, 2, 0) UNPK2(bB1.y, s1, 2, 2)
        UNPK2(bB1.z, s1, 3, 0) UNPK2(bB1.w, s1, 3, 2)

        __builtin_amdgcn_s_setprio(1);
#pragma unroll
        for (int sub = 0; sub < 4; ++sub) {
            const s16x8 kh0 = *(const s16x8*)(LB + cc + base0 + sub * 2048);
            const s16x8 kh1 = *(const s16x8*)(LB + cc + base1 + sub * 2048);
            const s16x8 kl0 = *(const s16x8*)(LB + cc + base0 + 8192 + sub * 2048);
            const s16x8 kl1 = *(const s16x8*)(LB + cc + base1 + 8192 + sub * 2048);
            s0[sub] = MFMA16(kh0, qh0_0, s0[sub], 0, 0, 0);
            s0[sub] = MFMA16(kh0, ql0_0, s0[sub], 0, 0, 0);
            s0[sub] = MFMA16(kl0, qh0_0, s0[sub], 0, 0, 0);
            s0[sub] = MFMA16(kh1, qh1_0, s0[sub], 0, 0, 0);
            s0[sub] = MFMA16(kh1, ql1_0, s0[sub], 0, 0, 0);
            s0[sub] = MFMA16(kl1, qh1_0, s0[sub], 0, 0, 0);
            s1[sub] = MFMA16(kh0, qh0_1, s1[sub], 0, 0, 0);
            s1[sub] = MFMA16(kh0, ql0_1, s1[sub], 0, 0, 0);
            s1[sub] = MFMA16(kl0, qh0_1, s1[sub], 0, 0, 0);
            s1[sub] = MFMA16(kh1, qh1_1, s1[sub], 0, 0, 0);
            s1[sub] = MFMA16(kh1, ql1_1, s1[sub], 0, 0, 0);
            s1[sub] = MFMA16(kl1, qh1_1, s1[sub], 0, 0, 0);
        }
        __builtin_amdgcn_s_setprio(0);

        float t0, t1;
        {
            float a = fmaxf(fmaxf(s0[0][0], s0[0][1]), s0[0][2]);
            float b = fmaxf(fmaxf(s0[0][3], s0[1][0]), s0[1][1]);
            float c = fmaxf(fmaxf(s0[1][2], s0[1][3]), s0[2][0]);
            float d = fmaxf(fmaxf(s0[2][1], s0[2][2]), s0[2][3]);
            float e = fmaxf(fmaxf(s0[3][0], s0[3][1]), s0[3][2]);
            t0 = fmaxf(fmaxf(fmaxf(a, b), fmaxf(c, d)), fmaxf(e, s0[3][3]));
        }
        {
            float a = fmaxf(fmaxf(s1[0][0], s1[0][1]), s1[0][2]);
            float b = fmaxf(fmaxf(s1[0][3], s1[1][0]), s1[1][1]);
            float c = fmaxf(fmaxf(s1[1][2], s1[1][3]), s1[2][0]);
            float d = fmaxf(fmaxf(s1[2][1], s1[2][2]), s1[2][3]);
            float e = fmaxf(fmaxf(s1[3][0], s1[3][1]), s1[3][2]);
            t1 = fmaxf(fmaxf(fmaxf(a, b), fmaxf(c, d)), fmaxf(e, s1[3][3]));
        }
        const int okd = (t0 <= m0 + DEFER_THR) && (t1 <= m1 + DEFER_THR);
        if (!__all(okd)) {
            float r0 = fmaxf(t0, __shfl_xor(t0, 16));
            r0 = fmaxf(r0, __shfl_xor(r0, 32));
            float r1 = fmaxf(t1, __shfl_xor(t1, 16));
            r1 = fmaxf(r1, __shfl_xor(r1, 32));
            const float mn0 = fmaxf(m0, r0), mn1 = fmaxf(m1, r1);
            const float sc0 = fexp2(m0 - mn0), sc1 = fexp2(m1 - mn1);
            m0 = mn0; m1 = mn1;
#pragma unroll
            for (int i = 0; i < 4; ++i) { O0[i] *= sc0; O1[i] *= sc1; }
            lacc0 *= sc0; lacc1 *= sc1;
        }
#pragma unroll
        for (int sub = 0; sub < 4; ++sub)
#pragma unroll
            for (int c = 0; c < 4; ++c) {
                s0[sub][c] = fexp2(s0[sub][c] - m0);
                s1[sub][c] = fexp2(s1[sub][c] - m1);
            }

        union { s16x8 v; unsigned int w[4]; } P00, P10, P01, P11;
        asm("v_cvt_pk_bf16_f32 %0, %1, %2" : "=v"(P00.w[0]) : "v"(s0[0][0]), "v"(s0[0][1]));
        asm("v_cvt_pk_bf16_f32 %0, %1, %2" : "=v"(P00.w[1]) : "v"(s0[0][2]), "v"(s0[0][3]));
        asm("v_cvt_pk_bf16_f32 %0, %1, %2" : "=v"(P00.w[2]) : "v"(s0[1][0]), "v"(s0[1][1]));
        asm("v_cvt_pk_bf16_f32 %0, %1, %2" : "=v"(P00.w[3]) : "v"(s0[1][2]), "v"(s0[1][3]));
        asm("v_cvt_pk_bf16_f32 %0, %1, %2" : "=v"(P10.w[0]) : "v"(s0[2][0]), "v"(s0[2][1]));
        asm("v_cvt_pk_bf16_f32 %0, %1, %2" : "=v"(P10.w[1]) : "v"(s0[2][2]), "v"(s0[2][3]));
        asm("v_cvt_pk_bf16_f32 %0, %1, %2" : "=v"(P10.w[2]) : "v"(s0[3][0]), "v"(s0[3][1]));
        asm("v_cvt_pk_bf16_f32 %0, %1, %2" : "=v"(P10.w[3]) : "v"(s0[3][2]), "v"(s0[3][3]));
        asm("v_cvt_pk_bf16_f32 %0, %1, %2" : "=v"(P01.w[0]) : "v"(s1[0][0]), "v"(s1[0][1]));
        asm("v_cvt_pk_bf16_f32 %0, %1, %2" : "=v"(P01.w[1]) : "v"(s1[0][2]), "v"(s1[0][3]));
        asm("v_cvt_pk_bf16_f32 %0, %1, %2" : "=v"(P01.w[2]) : "v"(s1[1][0]), "v"(s1[1][1]));
        asm("v_cvt_pk_bf16_f32 %0, %1, %2" : "=v"(P01.w[3]) : "v"(s1[1][2]), "v"(s1[1][3]));
        asm("v_cvt_pk_bf16_f32 %0, %1, %2" : "=v"(P11.w[0]) : "v"(s1[2][0]), "v"(s1[2][1]));
        asm("v_cvt_pk_bf16_f32 %0, %1, %2" : "=v"(P11.w[1]) : "v"(s1[2][2]), "v"(s1[2][3]));
        asm("v_cvt_pk_bf16_f32 %0, %1, %2" : "=v"(P11.w[2]) : "v"(s1[3][0]), "v"(s1[3][1]));
        asm("v_cvt_pk_bf16_f32 %0, %1, %2" : "=v"(P11.w[3]) : "v"(s1[3][2]), "v"(s1[3][3]));

        __builtin_amdgcn_s_setprio(1);
#pragma unroll
        for (int dsub = 0; dsub < 4; ++dsub) {
            const s16x8 vf0 = *(const s16x8*)(LB + cc + base0 + 16384 + dsub * 2048);
            const s16x8 vf1 = *(const s16x8*)(LB + cc + base1 + 16384 + dsub * 2048);
            O0[dsub] = MFMA16(vf0, P00.v, O0[dsub], 0, 0, 0);
            O0[dsub] = MFMA16(vf1, P10.v, O0[dsub], 0, 0, 0);
            O1[dsub] = MFMA16(vf0, P01.v, O1[dsub], 0, 0, 0);
            O1[dsub] = MFMA16(vf1, P11.v, O1[dsub], 0, 0, 0);
        }
        lacc0 = MFMA16(ones, P00.v, lacc0, 0, 0, 0);
        lacc0 = MFMA16(ones, P10.v, lacc0, 0, 0, 0);
        lacc1 = MFMA16(ones, P01.v, lacc1, 0, 0, 0);
        lacc1 = MFMA16(ones, P11.v, lacc1, 0, 0, 0);
        __builtin_amdgcn_s_setprio(0);

        asm volatile("s_waitcnt vmcnt(3)" ::: "memory");
        __builtin_amdgcn_s_barrier();
        __builtin_amdgcn_sched_barrier(0);
        cc += BUFB; if (cc == 3 * BUFB) cc = 0;
        cs += BUFB; if (cs == 3 * BUFB) cs = 0;
    }

    // ---- write unnormalized bf16 partials + (m,l) ----
#pragma unroll
    for (int qs = 0; qs < 2; ++qs) {
        const int qr = qt * 256 + qs * 128 + wv * 16 + li;
        const f32x4* Oq = qs ? O1 : O0;
        const float mq = qs ? m1 : m0;
        const float lq = qs ? lacc1[0] : lacc0[0];
        unsigned short* pb = Opart + ((size_t)(split * 32 + bh) * 2048 + qr) * 64;
#pragma unroll
        for (int dsub = 0; dsub < 4; ++dsub) {
            u16x4 pk;
#pragma unroll
            for (int c = 0; c < 4; ++c) pk[c] = f2bf(Oq[dsub][c]);
            *(u16x4*)(pb + dsub * 16 + 4 * g) = pk;
        }
        if (g == 0)
            ML[(size_t)split * 65536 + (size_t)bh * 2048 + qr] = make_float2(mq, lq);
    }
#undef STAGE2
#undef UNPK2
}

// ---------------------------------------------------------------------------
// Kernel 3c: merge split-K partials -> normalized bf16 tiled AOb.
// ---------------------------------------------------------------------------
__global__ __launch_bounds__(256) void merge_kernel(
    const unsigned short* __restrict__ Opart, const float2* __restrict__ ML,
    unsigned short* __restrict__ AOb)
{
    const int idx = blockIdx.x * 256 + threadIdx.x;    // 65536 = bh*2048 + q
    const int bh = idx >> 11, q = idx & 2047;
    const float2 a = ML[idx];
    const float2 b = ML[65536 + idx];
    const float M = fmaxf(a.x, b.x);
    const float s0 = fexp2(a.x - M), s1 = fexp2(b.x - M);
    const float l = a.y * s0 + b.y * s1;
    const float w0 = s0 / l, w1 = s1 / l;
    const unsigned short* p0 = Opart + (size_t)idx * 64;
    const unsigned short* p1 = p0 + 4194304;           // +32*2048*64

    const int bb = bh >> 3, hh = bh & 7;
    const int row = bb * 2048 + q;
    const int r128 = row & 127;
    const int xr = (r128 >> 1) & 3;
    unsigned short* __restrict__ ab = AOb + ((size_t)(row >> 7)) * 65536 + r128 * 32;
#pragma unroll
    for (int d0 = 0; d0 < 64; d0 += 4) {
        const u16x4 x = *(const u16x4*)(p0 + d0);
        const u16x4 y = *(const u16x4*)(p1 + d0);
        u16x4 o;
#pragma unroll
        for (int c = 0; c < 4; ++c)
            o[c] = f2bf(bf2f(x[c]) * w0 + bf2f(y[c]) * w1);
        const int dsub = d0 >> 4, gq = (d0 >> 2) & 3;
        const int ch = hh * 2 + (dsub >> 1);
        const int slot = ((dsub & 1) * 2 + (gq >> 1)) ^ xr;
        *(u16x4*)(ab + (gq & 1) * 4 + (size_t)ch * 4096 + slot * 8) = o;
    }
}

// ---------------------------------------------------------------------------
// Kernel 4: MFMA epilogue GEMM AObf[8192,512] @ WO[512,384pad] -> out fp32.
// ---------------------------------------------------------------------------
__global__ __launch_bounds__(256) void epi_mfma_kernel(
    const unsigned short* __restrict__ AOb, const unsigned short* __restrict__ WOT,
    float* __restrict__ out)
{
    const int stile = blockIdx.x, jtile = blockIdx.y;
    const int tid = threadIdx.x, wv = tid >> 6, lane = tid & 63;
    const int li = lane & 15, g = lane >> 4;

    __shared__ __align__(16) char LBe[24576];

    const unsigned short* __restrict__ pA =
        AOb + (size_t)(stile >> 1) * 65536 + (stile & 1) * 2048 + tid * 8;
    const unsigned short* __restrict__ pW = WOT + (size_t)jtile * 65536 + tid * 8;

#define STAGEE(ch, bofs) {                                                    \
        char* dbA = LBe + (bofs) + wv * 1024;                                 \
        const size_t co = (size_t)(ch) * 4096;                                \
        gload16(pA + co,        dbA);                                         \
        gload16(pW + co,        dbA + 4096);                                  \
        gload16(pW + co + 2048, dbA + 8192);                                  \
    }

    int offA[4], offW[2];
#pragma unroll
    for (int ssub = 0; ssub < 4; ++ssub) {
        const int r = ssub * 16 + li;
        offA[ssub] = r * 64 + ((g ^ ((r >> 1) & 3)) << 4);
    }
#pragma unroll
    for (int jsub = 0; jsub < 2; ++jsub) {
        const int n = wv * 32 + jsub * 16 + li;
        offW[jsub] = 4096 + n * 64 + ((g ^ ((n >> 1) & 3)) << 4);
    }

    f32x4 acc[4][2];
#pragma unroll
    for (int i = 0; i < 4; ++i)
#pragma unroll
        for (int j = 0; j < 2; ++j) acc[i][j] = (f32x4){0.f, 0.f, 0.f, 0.f};

    STAGEE(0, 0)
    __syncthreads();

#pragma unroll 1
    for (int ch = 0; ch < 16; ++ch) {
        const int bofs = (ch & 1) * 12288;
        if (ch < 15) STAGEE(ch + 1, bofs ^ 12288)
        const char* bp = LBe + bofs;
        s16x8 ah[4], wh[2];
#pragma unroll
        for (int ssub = 0; ssub < 4; ++ssub)
            ah[ssub] = *(const s16x8*)(bp + offA[ssub]);
#pragma unroll
        for (int jsub = 0; jsub < 2; ++jsub)
            wh[jsub] = *(const s16x8*)(bp + offW[jsub]);
        __builtin_amdgcn_s_setprio(1);
#pragma unroll
        for (int ssub = 0; ssub < 4; ++ssub)
#pragma unroll
            for (int jsub = 0; jsub < 2; ++jsub)
                acc[ssub][jsub] = MFMA16(ah[ssub], wh[jsub], acc[ssub][jsub], 0, 0, 0);
        __builtin_amdgcn_s_setprio(0);
        __syncthreads();
    }
#undef STAGEE

    const int nbase = jtile * 128 + wv * 32 + li;
    const int rbase = stile * 64 + 4 * g;
#pragma unroll
    for (int jsub = 0; jsub < 2; ++jsub) {
        const int o = nbase + jsub * 16;
        if (o < HIDIN) {
#pragma unroll
            for (int ssub = 0; ssub < 4; ++ssub) {
                const f32x4 v = acc[ssub][jsub];
                const int r0 = rbase + ssub * 16;
#pragma unroll
                for (int r = 0; r < 4; ++r)
                    out[(size_t)(r0 + r) * HIDIN + o] = v[r];
            }
        }
    }
}

// ---------------------------------------------------------------------------
extern "C" void kernel_launch(void* const* d_in, const int* in_sizes, int n_in,
                              void* d_out, int out_size, void* d_ws, size_t ws_size,
                              hipStream_t stream)
{
    const float* en  = (const float*)d_in[0];
    const float* de  = (const float*)d_in[1];
    const int*   mask = (const int*)d_in[2];
    const float* WQ  = (const float*)d_in[3];
    const float* WK  = (const float*)d_in[4];
    const float* WV  = (const float*)d_in[5];
    const float* WO  = (const float*)d_in[6];
    float* out = (float*)d_out;

    unsigned short* ws2 = (unsigned short*)d_ws;
    unsigned short* Qh  = ws2 + OF_QH;
    unsigned short* Ql  = ws2 + OF_QL;
    unsigned short* KhT = ws2 + OF_KH;
    unsigned short* KlT = ws2 + OF_KL;
    unsigned short* VtT = ws2 + OF_VT;
    unsigned short* CA  = ws2 + OF_CA;
    unsigned short* CW  = ws2 + OF_CW;
    unsigned short* WOT = ws2 + OF_WOT;
    unsigned short* AOb = CA;                                 // aliases conv-A (dead after proj)
    unsigned int*  BiasT = (unsigned int*)(CA + 4194304);     // aliases conv-A tail

    convA_kernel<<<dim3(320, 2), 256, 0, stream>>>(de, en, CA);
    convW_kernel<<<dim3(672), 256, 0, stream>>>(WQ, WK, WV, WO, CW, WOT);
    proj_qk_kernel<<<dim3(512), 256, 0, stream>>>(CA, CW, Qh, Ql, KhT, KlT);
    proj_v_kernel<<<dim3(256), 256, 0, stream>>>(CA, CW, VtT);
    bias_kernel<<<dim3(256), 256, 0, stream>>>(mask, BiasT);

    if (ws_size >= WS_NEED_SPLIT) {
        unsigned short* Opart = ws2 + OF_PART;
        float2* ML = (float2*)(ws2 + OF_PART + 8388608);
        attn2_kernel<<<dim3(16, 32), 512, 0, stream>>>(Qh, Ql, KhT, KlT, VtT,
                                                       BiasT, Opart, ML);
        merge_kernel<<<dim3(256), 256, 0, stream>>>(Opart, ML, AOb);
    } else {
        attn_mfma_kernel<<<dim3(16, 32), 512, 0, stream>>>(Qh, Ql, KhT, KlT, VtT,
                                                           BiasT, AOb);
    }
    epi_mfma_kernel<<<dim3(128, 3), 256, 0, stream>>>(AOb, WOT, out);
}

// Round 16
// 176.179 us; speedup vs baseline: 1.1681x; 1.1681x over previous
//
#include <hip/hip_runtime.h>
#include <hip/hip_bf16.h>
#include <math.h>

#define B_      4
#define SD_     2048
#define SE_     2048
#define HIDIN   300
#define HIDMID  512
#define NH      8
#define DH      64
#define ESZ     ((size_t)4194304)          // elems per [32][2048][64] tensor
#define BUFB    24576                       // bytes per attn LDS buffer (Kh+Kl+V)

typedef __attribute__((ext_vector_type(8))) short          s16x8;
typedef __attribute__((ext_vector_type(8))) unsigned short u16x8;
typedef __attribute__((ext_vector_type(4))) unsigned short u16x4;
typedef __attribute__((ext_vector_type(4))) float          f32x4;

#define MFMA16 __builtin_amdgcn_mfma_f32_16x16x32_bf16

// logit scale: (1/sqrt(300)) * log2(e)  -> softmax done in base-2
#define QSCALE  0.0832940411f
#define NEGL   -1.4426950e9f               // -1e9 * log2e
#define DEFER_THR 24.0f                    // defer-max threshold (base-2 units)

__device__ __forceinline__ unsigned short f2bf(float f) {
    unsigned int u = __float_as_uint(f);
    u += 0x7fffu + ((u >> 16) & 1u);          // RNE
    return (unsigned short)(u >> 16);
}
__device__ __forceinline__ float bf2f(unsigned short s) {
    return __uint_as_float((unsigned int)s << 16);
}
__device__ __forceinline__ void gload16(const void* g, void* l) {
    __builtin_amdgcn_global_load_lds(
        (const __attribute__((address_space(1))) void*)g,
        (__attribute__((address_space(3))) void*)l, 16, 0, 0);
}
// Raw v_exp_f32 (no OCML denormal fixup): inputs <= ~0; anything < -126
// underflows to 0, exactly what softmax wants (masked -1.4e9 -> 0, no NaN).
__device__ __forceinline__ float fexp2(float x) {
#if __has_builtin(__builtin_amdgcn_exp2f)
    return __builtin_amdgcn_exp2f(x);
#else
    return exp2f(x);
#endif
}

// ws ushort offsets
#define OF_QH   ((size_t)0)
#define OF_QL   (ESZ)
#define OF_KH   (2*ESZ)
#define OF_KL   (3*ESZ)
#define OF_VT   (4*ESZ)
#define OF_CA   (5*ESZ)                    // deH,deL,enH,enL (4 x 2621440)
#define OF_CW   (OF_CA + 10485760)         // WQh,WQl,WKh,WKl,WVh,WVl (6 x 163840)
#define OF_WOT  (OF_CW + 983040)           // 196608

// ---------------------------------------------------------------------------
// Kernel 0 (runs AFTER proj; lives in dead conv-A ws): mask (int32) ->
// packed-bf16-pair bias table {0, NEGL}. Pre-softmax additive bias keeps the
// running max masked-aware (numerically REQUIRED — see R12 NaN post-mortem).
// addr(u32) = ((((q>>4)*32 + tile)*4 + g)*16 + (q&15))*8, elem = sub*4+c,
// t = sub*16 + g*4 + c.
// ---------------------------------------------------------------------------
__global__ __launch_bounds__(256) void bias_kernel(const int* __restrict__ mask,
                                                   unsigned int* __restrict__ BiasT)
{
    const int idx = blockIdx.x * 256 + threadIdx.x;    // 65536 threads
    const int q = idx >> 5, tile = idx & 31;
    const int* __restrict__ mrow = mask + (size_t)q * SE_ + tile * 64;
    const unsigned int NEGB = (unsigned int)f2bf(NEGL);
    const int qblk = q >> 4, qlo = q & 15;
#pragma unroll
    for (int g = 0; g < 4; ++g) {
        unsigned int w[8];
#pragma unroll
        for (int sub = 0; sub < 4; ++sub) {
            const int4 mm = *(const int4*)(mrow + sub * 16 + g * 4);
            w[sub * 2]     = (mm.x ? NEGB : 0u) | ((mm.y ? NEGB : 0u) << 16);
            w[sub * 2 + 1] = (mm.z ? NEGB : 0u) | ((mm.w ? NEGB : 0u) << 16);
        }
        unsigned int* dst = BiasT +
            ((((size_t)qblk * 32 + tile) * 4 + g) * 16 + qlo) * 8;
        *(uint4*)dst       = make_uint4(w[0], w[1], w[2], w[3]);
        *(uint4*)(dst + 4) = make_uint4(w[4], w[5], w[6], w[7]);
    }
}

// ---------------------------------------------------------------------------
// Kernel 1a: de/en fp32 -> split bf16 hi/lo, tiled GEMM-A layout.
// ---------------------------------------------------------------------------
__global__ __launch_bounds__(256) void convA_kernel(
    const float* __restrict__ de, const float* __restrict__ en,
    unsigned short* __restrict__ CA)
{
    const int idx = blockIdx.x * 256 + threadIdx.x;    // 81920 per matrix
    const int mat = blockIdx.y;
    const float* __restrict__ A = mat ? en : de;
    unsigned short* __restrict__ H = CA + (size_t)mat * 5242880;
    unsigned short* __restrict__ L = H + 2621440;
    const int row = idx / 10, ch = idx - row * 10;
    float v[32];
    if (ch < 9) {
#pragma unroll
        for (int i = 0; i < 8; ++i) {
            const float4 f = *(const float4*)(A + (size_t)row * 300 + ch * 32 + i * 4);
            v[i*4+0] = f.x; v[i*4+1] = f.y; v[i*4+2] = f.z; v[i*4+3] = f.w;
        }
    } else {
#pragma unroll
        for (int i = 0; i < 32; ++i) {
            const int k = 288 + i;
            v[i] = (k < 300) ? A[(size_t)row * 300 + k] : 0.f;
        }
    }
    const int r128 = row & 127;
    const int xr = (r128 >> 1) & 3;
    const size_t tb = ((size_t)(row >> 7) * 10 + ch) * 4096 + r128 * 32;
#pragma unroll
    for (int sub = 0; sub < 4; ++sub) {
        const int slot = sub ^ xr;
        u16x8 hv, lv;
#pragma unroll
        for (int e = 0; e < 8; ++e) {
            const float f = v[sub * 8 + e];
            const unsigned short h = f2bf(f);
            hv[e] = h; lv[e] = f2bf(f - bf2f(h));
        }
        *(u16x8*)(H + tb + slot * 8) = hv;
        *(u16x8*)(L + tb + slot * 8) = lv;
    }
}

// ---------------------------------------------------------------------------
// Kernel 1b: WQ/WK -> split bf16 hi/lo transposed tiled (QSCALE folded into
// WQ); WV hi only; WO -> plain bf16 transposed tiled (n padded 300->384).
// ---------------------------------------------------------------------------
__global__ __launch_bounds__(256) void convW_kernel(
    const float* __restrict__ WQ, const float* __restrict__ WK,
    const float* __restrict__ WV, const float* __restrict__ WO,
    unsigned short* __restrict__ CW, unsigned short* __restrict__ WOT)
{
    const int idx = blockIdx.x * 256 + threadIdx.x;
    if (idx < 122880) {                       // QKV: which x k(320) x n4(128)
        const int which = idx / 40960;
        const int rem = idx - which * 40960;
        const int k = rem >> 7;
        const int n0 = (rem & 127) * 4;
        const float* __restrict__ W = which == 0 ? WQ : (which == 1 ? WK : WV);
        unsigned short* __restrict__ H = CW + (size_t)which * 327680;
        unsigned short* __restrict__ L = H + 163840;
        const float sc = (which == 0) ? QSCALE : 1.f;
        float4 w = make_float4(0.f, 0.f, 0.f, 0.f);
        if (k < 300) w = *(const float4*)(W + (size_t)k * 512 + n0);
        const float wv4[4] = {w.x * sc, w.y * sc, w.z * sc, w.w * sc};
        const int ch = k >> 5, kk = k & 31;
#pragma unroll
        for (int j = 0; j < 4; ++j) {
            const int n = n0 + j, ntile = n >> 7, nr = n & 127;
            const size_t o = ((size_t)(ntile * 10 + ch) * 128 + nr) * 32
                           + (((kk >> 3) ^ ((nr >> 1) & 3)) << 3) + (kk & 7);
            const unsigned short h = f2bf(wv4[j]);
            H[o] = h;
            if (which < 2) L[o] = f2bf(wv4[j] - bf2f(h));
        }
    } else {                                   // WO: k(512) x n4(96)
        const int idx2 = idx - 122880;
        const int k = idx2 / 96, n4 = idx2 - k * 96;
        const int n0 = n4 * 4;
        float4 w = make_float4(0.f, 0.f, 0.f, 0.f);
        if (n0 < 300) w = *(const float4*)(WO + (size_t)k * 300 + n0);
        const float wv4[4] = {w.x, w.y, w.z, w.w};
        const int ch = k >> 5, kk = k & 31;
#pragma unroll
        for (int j = 0; j < 4; ++j) {
            const int n = n0 + j, ntile = n >> 7, nr = n & 127;
            const size_t o = ((size_t)(ntile * 16 + ch) * 128 + nr) * 32
                           + (((kk >> 3) ^ ((nr >> 1) & 3)) << 3) + (kk & 7);
            WOT[o] = f2bf(wv4[j]);
        }
    }
}

// ---------------------------------------------------------------------------
// Kernel 2a: MFMA Q/K projection (3-term). 512 blocks = exactly 2/CU, one
// full dispatch wave. XCD swizzle keeps same-A-panel jtiles on one XCD.
// ---------------------------------------------------------------------------
__global__ __launch_bounds__(256) void proj_qk_kernel(
    const unsigned short* __restrict__ CA, const unsigned short* __restrict__ CW,
    unsigned short* __restrict__ Qh, unsigned short* __restrict__ Ql,
    unsigned short* __restrict__ KhT, unsigned short* __restrict__ KlT)
{
    const int lin = blockIdx.x;
    const int which = lin >> 8;                        // 0=Q, 1=K
    const int t = lin & 255;
    const int stile = (t & 7) | ((t >> 5) << 3);
    const int jtile = (t >> 3) & 3;
    const int tid = threadIdx.x, wv = tid >> 6, lane = tid & 63;
    const int li = lane & 15, g = lane >> 4;
    const int wr = wv >> 1, wc = wv & 1;

    __shared__ __align__(16) char LBp[65536];   // 2 bufs x (Ah|Al|Wh|Wl) x 8KB

    const unsigned short* __restrict__ pAh =
        CA + (size_t)which * 5242880 + (size_t)stile * 40960 + tid * 8;
    const unsigned short* __restrict__ pAl = pAh + 2621440;
    const unsigned short* __restrict__ pWh =
        CW + (size_t)which * 327680 + (size_t)jtile * 40960 + tid * 8;
    const unsigned short* __restrict__ pWl = pWh + 163840;

#define STAGEP(ch, bofs) {                                                    \
        char* db = LBp + (bofs) + wv * 1024;                                  \
        const size_t co = (size_t)(ch) * 4096;                                \
        gload16(pAh + co,        db);                                         \
        gload16(pAh + co + 2048, db + 4096);                                  \
        gload16(pAl + co,        db + 8192);                                  \
        gload16(pAl + co + 2048, db + 12288);                                 \
        gload16(pWh + co,        db + 16384);                                 \
        gload16(pWh + co + 2048, db + 20480);                                 \
        gload16(pWl + co,        db + 24576);                                 \
        gload16(pWl + co + 2048, db + 28672);                                 \
    }

    int offA[4], offW[4];
#pragma unroll
    for (int ssub = 0; ssub < 4; ++ssub) {
        const int r = wr * 64 + ssub * 16 + li;
        offA[ssub] = r * 64 + ((g ^ ((r >> 1) & 3)) << 4);
    }
#pragma unroll
    for (int jsub = 0; jsub < 4; ++jsub) {
        const int n = wc * 64 + jsub * 16 + li;
        offW[jsub] = n * 64 + ((g ^ ((n >> 1) & 3)) << 4);
    }

    f32x4 acc[4][4];
#pragma unroll
    for (int i = 0; i < 4; ++i)
#pragma unroll
        for (int j = 0; j < 4; ++j) acc[i][j] = (f32x4){0.f, 0.f, 0.f, 0.f};

    STAGEP(0, 0)
    __syncthreads();

#pragma unroll 1
    for (int ch = 0; ch < 10; ++ch) {
        const int bofs = (ch & 1) * 32768;
        if (ch < 9) STAGEP(ch + 1, bofs ^ 32768)
        const char* bp = LBp + bofs;
        s16x8 ah[4], al[4], wh[4], wl[4];
#pragma unroll
        for (int ssub = 0; ssub < 4; ++ssub) {
            ah[ssub] = *(const s16x8*)(bp + offA[ssub]);
            al[ssub] = *(const s16x8*)(bp + 8192 + offA[ssub]);
        }
#pragma unroll
        for (int jsub = 0; jsub < 4; ++jsub) {
            wh[jsub] = *(const s16x8*)(bp + 16384 + offW[jsub]);
            wl[jsub] = *(const s16x8*)(bp + 24576 + offW[jsub]);
        }
        __builtin_amdgcn_s_setprio(1);
#pragma unroll
        for (int ssub = 0; ssub < 4; ++ssub)
#pragma unroll
            for (int jsub = 0; jsub < 4; ++jsub) {
                acc[ssub][jsub] = MFMA16(ah[ssub], wh[jsub], acc[ssub][jsub], 0, 0, 0);
                acc[ssub][jsub] = MFMA16(ah[ssub], wl[jsub], acc[ssub][jsub], 0, 0, 0);
                acc[ssub][jsub] = MFMA16(al[ssub], wh[jsub], acc[ssub][jsub], 0, 0, 0);
            }
        __builtin_amdgcn_s_setprio(0);
        __syncthreads();
    }
#undef STAGEP

    const int jgbase = jtile * 128 + wc * 64 + li;
    const int sbase0 = stile * 128 + wr * 64 + 4 * g;
#pragma unroll
    for (int jsub = 0; jsub < 4; ++jsub) {
        const int jgg = jgbase + jsub * 16;
        const int d = jgg >> 3, hh = jgg & 7;
#pragma unroll
        for (int ssub = 0; ssub < 4; ++ssub) {
            const f32x4 v = acc[ssub][jsub];
            const int sg0 = sbase0 + ssub * 16;
            const int bbv = sg0 >> 11;
            const int bhn = bbv * 8 + hh;
            const int sl0 = sg0 & 2047;
            if (which == 0) {
                const size_t o = ((size_t)bhn * 2048 + sl0) * 64 + d;
#pragma unroll
                for (int r = 0; r < 4; ++r) {
                    const float val = v[r];
                    const unsigned short hi = f2bf(val);
                    Qh[o + r * 64] = hi;
                    Ql[o + r * 64] = f2bf(val - bf2f(hi));
                }
            } else {
                const int tile = sl0 >> 6, tt0 = sl0 & 63;
                const size_t tb = ((size_t)(bhn * 32 + tile)) << 12;
#pragma unroll
                for (int r = 0; r < 4; ++r) {
                    const int tt = tt0 + r;
                    const size_t o = tb + tt * 64 + (((d >> 3) ^ (tt & 7)) << 3) + (d & 7);
                    const float val = v[r];
                    const unsigned short hi = f2bf(val);
                    KhT[o] = hi;
                    KlT[o] = f2bf(val - bf2f(hi));
                }
            }
        }
    }
}

// ---------------------------------------------------------------------------
// Kernel 2b: MFMA V projection (1-term, Ah*Wh). 256 blocks, 32 KB LDS.
// ---------------------------------------------------------------------------
__global__ __launch_bounds__(256) void proj_v_kernel(
    const unsigned short* __restrict__ CA, const unsigned short* __restrict__ CW,
    unsigned short* __restrict__ VtT)
{
    const int t = blockIdx.x;
    const int stile = (t & 7) | ((t >> 5) << 3);
    const int jtile = (t >> 3) & 3;
    const int tid = threadIdx.x, wv = tid >> 6, lane = tid & 63;
    const int li = lane & 15, g = lane >> 4;
    const int wr = wv >> 1, wc = wv & 1;

    __shared__ __align__(16) char LBv[32768];   // 2 bufs x (Ah|Wh) x 8KB

    const unsigned short* __restrict__ pAh =
        CA + (size_t)1 * 5242880 + (size_t)stile * 40960 + tid * 8;   // en hi
    const unsigned short* __restrict__ pWh =
        CW + (size_t)2 * 327680 + (size_t)jtile * 40960 + tid * 8;    // WV hi

#define STAGEV(ch, bofs) {                                                    \
        char* db = LBv + (bofs) + wv * 1024;                                  \
        const size_t co = (size_t)(ch) * 4096;                                \
        gload16(pAh + co,        db);                                         \
        gload16(pAh + co + 2048, db + 4096);                                  \
        gload16(pWh + co,        db + 8192);                                  \
        gload16(pWh + co + 2048, db + 12288);                                 \
    }

    int offA[4], offW[4];
#pragma unroll
    for (int ssub = 0; ssub < 4; ++ssub) {
        const int r = wr * 64 + ssub * 16 + li;
        offA[ssub] = r * 64 + ((g ^ ((r >> 1) & 3)) << 4);
    }
#pragma unroll
    for (int jsub = 0; jsub < 4; ++jsub) {
        const int n = wc * 64 + jsub * 16 + li;
        offW[jsub] = 8192 + n * 64 + ((g ^ ((n >> 1) & 3)) << 4);
    }

    f32x4 acc[4][4];
#pragma unroll
    for (int i = 0; i < 4; ++i)
#pragma unroll
        for (int j = 0; j < 4; ++j) acc[i][j] = (f32x4){0.f, 0.f, 0.f, 0.f};

    STAGEV(0, 0)
    __syncthreads();

#pragma unroll 1
    for (int ch = 0; ch < 10; ++ch) {
        const int bofs = (ch & 1) * 16384;
        if (ch < 9) STAGEV(ch + 1, bofs ^ 16384)
        const char* bp = LBv + bofs;
        s16x8 ah[4], wh[4];
#pragma unroll
        for (int ssub = 0; ssub < 4; ++ssub)
            ah[ssub] = *(const s16x8*)(bp + offA[ssub]);
#pragma unroll
        for (int jsub = 0; jsub < 4; ++jsub)
            wh[jsub] = *(const s16x8*)(bp + offW[jsub]);
        __builtin_amdgcn_s_setprio(1);
#pragma unroll
        for (int ssub = 0; ssub < 4; ++ssub)
#pragma unroll
            for (int jsub = 0; jsub < 4; ++jsub)
                acc[ssub][jsub] = MFMA16(ah[ssub], wh[jsub], acc[ssub][jsub], 0, 0, 0);
        __builtin_amdgcn_s_setprio(0);
        __syncthreads();
    }
#undef STAGEV

    const int jgbase = jtile * 128 + wc * 64 + li;
    const int sbase0 = stile * 128 + wr * 64 + 4 * g;
#pragma unroll
    for (int jsub = 0; jsub < 4; ++jsub) {
        const int jgg = jgbase + jsub * 16;
        const int d = jgg >> 3, hh = jgg & 7;
#pragma unroll
        for (int ssub = 0; ssub < 4; ++ssub) {
            const f32x4 v = acc[ssub][jsub];
            const int sg0 = sbase0 + ssub * 16;
            const int bbv = sg0 >> 11;
            const int bhn = bbv * 8 + hh;
            const int sl0 = sg0 & 2047;
            const int tile = sl0 >> 6, tin0 = sl0 & 63;
            const size_t tb = ((size_t)(bhn * 32 + tile)) << 12;
            const int blk = tin0 >> 5, gg2 = (tin0 >> 2) & 3, half = (tin0 >> 4) & 1;
            const size_t o = tb + (size_t)d * 64
                           + ((((blk << 2) | gg2) ^ (d & 7)) << 3) + half * 4;
            u16x4 pk;
#pragma unroll
            for (int r = 0; r < 4; ++r) pk[r] = f2bf(v[r]);
            *(u16x4*)(VtT + o) = pk;
        }
    }
}

// ---------------------------------------------------------------------------
// Kernel 3: MFMA flash attention (R14-verified). 3-term S, 8 waves x 16 q,
// 3-buffer ring + counted vmcnt(3), setprio, XCD swizzle, defer-max,
// bf16-pair bias table (pre-softmax, masked-aware max), ones-l, raw exp2.
// ---------------------------------------------------------------------------
__global__ __launch_bounds__(512, 4) void attn_mfma_kernel(
    const unsigned short* __restrict__ Qh, const unsigned short* __restrict__ Ql,
    const unsigned short* __restrict__ KhT, const unsigned short* __restrict__ KlT,
    const unsigned short* __restrict__ VtT, const unsigned int* __restrict__ BiasT,
    unsigned short* __restrict__ AOb)
{
    const int lin = blockIdx.x + 16 * blockIdx.y;
    const int qt = (lin >> 3) & 15;
    const int bh = (lin & 7) + ((lin >> 7) << 3);
    const int bb = bh >> 3, hh = bh & 7;
    const int tid = threadIdx.x;
    const int wv = tid >> 6, lane = tid & 63;
    const int g = lane >> 4, li = lane & 15;
    const int q = qt * 128 + wv * 16 + li;

    __shared__ __align__(16) char LB[3 * BUFB];       // 72 KB

    const size_t qoff = ((size_t)bh * SD_ + q) * DH + 8 * g;
    const s16x8 qh0 = *(const s16x8*)(Qh + qoff);
    const s16x8 qh1 = *(const s16x8*)(Qh + qoff + 32);
    const s16x8 ql0 = *(const s16x8*)(Ql + qoff);
    const s16x8 ql1 = *(const s16x8*)(Ql + qoff + 32);

    const unsigned short* __restrict__ sKh = KhT + ((size_t)bh << 17) + tid * 8;
    const unsigned short* __restrict__ sKl = KlT + ((size_t)bh << 17) + tid * 8;
    const unsigned short* __restrict__ sVt = VtT + ((size_t)bh << 17) + tid * 8;

    const int base0 = li * 128 + ((g ^ (li & 7)) << 4);
    const int base1 = li * 128 + (((4 + g) ^ (li & 7)) << 4);

    // bias table base (u32 units); per-tile stride = 512 u32
    const size_t bbase = (size_t)(qt * 8 + wv) * 16384 + g * 128 + li * 8;

#define BIASLOAD(T, RA, RB) {                                                 \
        const uint4* p = (const uint4*)(BiasT + bbase + (size_t)(T) * 512);   \
        RA = p[0]; RB = p[1];                                                 \
    }
#define STAGE(tile, boff)                                                     \
    {                                                                         \
        char* db = LB + (boff) + wv * 1024;                                   \
        const size_t toff = (size_t)(tile) << 12;                             \
        gload16(sKh + toff, db);                                              \
        gload16(sKl + toff, db + 8192);                                       \
        gload16(sVt + toff, db + 16384);                                      \
    }

    float m = -INFINITY;
    f32x4 O[4], lacc;
#pragma unroll
    for (int i = 0; i < 4; ++i) O[i] = (f32x4){0.f, 0.f, 0.f, 0.f};
    lacc = (f32x4){0.f, 0.f, 0.f, 0.f};

    s16x8 ones;
#pragma unroll
    for (int i = 0; i < 8; ++i) ones[i] = (short)0x3F80;

    uint4 cBA, cBB, nBA, nBB;

#define UNPK(W, S, sub, cbase)                                                \
        S[sub][cbase]     = __uint_as_float((W) << 16);                       \
        S[sub][cbase + 1] = __uint_as_float((W) & 0xFFFF0000u);

#define ITER(IT, CBA_, CBB_, NBA_, NBB_)                                      \
    {                                                                         \
        BIASLOAD(((IT) + 1) & 31, NBA_, NBB_)                                 \
        STAGE(((IT) + 2) & 31, cs)                                            \
        f32x4 s[4];                                                           \
        UNPK(CBA_.x, s, 0, 0) UNPK(CBA_.y, s, 0, 2)                           \
        UNPK(CBA_.z, s, 1, 0) UNPK(CBA_.w, s, 1, 2)                           \
        UNPK(CBB_.x, s, 2, 0) UNPK(CBB_.y, s, 2, 2)                           \
        UNPK(CBB_.z, s, 3, 0) UNPK(CBB_.w, s, 3, 2)                           \
        __builtin_amdgcn_s_setprio(1);                                        \
        _Pragma("unroll")                                                     \
        for (int sub = 0; sub < 4; ++sub) {                                   \
            const s16x8 kh0 = *(const s16x8*)(LB + cc + base0 + sub * 2048);  \
            const s16x8 kh1 = *(const s16x8*)(LB + cc + base1 + sub * 2048);  \
            const s16x8 kl0 = *(const s16x8*)(LB + cc + base0 + 8192 + sub * 2048); \
            const s16x8 kl1 = *(const s16x8*)(LB + cc + base1 + 8192 + sub * 2048); \
            s[sub] = MFMA16(kh0, qh0, s[sub], 0, 0, 0);                       \
            s[sub] = MFMA16(kh0, ql0, s[sub], 0, 0, 0);                       \
            s[sub] = MFMA16(kl0, qh0, s[sub], 0, 0, 0);                       \
            s[sub] = MFMA16(kh1, qh1, s[sub], 0, 0, 0);                       \
            s[sub] = MFMA16(kh1, ql1, s[sub], 0, 0, 0);                       \
            s[sub] = MFMA16(kl1, qh1, s[sub], 0, 0, 0);                       \
        }                                                                     \
        __builtin_amdgcn_s_setprio(0);                                        \
        float x0 = fmaxf(fmaxf(s[0][0], s[0][1]), s[0][2]);                   \
        float x1 = fmaxf(fmaxf(s[0][3], s[1][0]), s[1][1]);                   \
        float x2 = fmaxf(fmaxf(s[1][2], s[1][3]), s[2][0]);                   \
        float x3 = fmaxf(fmaxf(s[2][1], s[2][2]), s[2][3]);                   \
        float x4 = fmaxf(fmaxf(s[3][0], s[3][1]), s[3][2]);                   \
        float tmax = fmaxf(fmaxf(fmaxf(x0, x1), fmaxf(x2, x3)),               \
                           fmaxf(x4, s[3][3]));                               \
        if (!__all(tmax <= m + DEFER_THR)) {                                  \
            float r = fmaxf(tmax, __shfl_xor(tmax, 16));                      \
            r = fmaxf(r, __shfl_xor(r, 32));                                  \
            const float mn  = fmaxf(m, r);                                    \
            const float scl = fexp2(m - mn);                                  \
            m = mn;                                                           \
            _Pragma("unroll")                                                 \
            for (int i = 0; i < 4; ++i) O[i] *= scl;                          \
            lacc *= scl;                                                      \
        }                                                                     \
        _Pragma("unroll")                                                     \
        for (int sub = 0; sub < 4; ++sub)                                     \
            _Pragma("unroll")                                                 \
            for (int c = 0; c < 4; ++c)                                       \
                s[sub][c] = fexp2(s[sub][c] - m);                             \
        union { s16x8 v; unsigned int w[4]; } P0, P1;                         \
        asm("v_cvt_pk_bf16_f32 %0, %1, %2" : "=v"(P0.w[0]) : "v"(s[0][0]), "v"(s[0][1])); \
        asm("v_cvt_pk_bf16_f32 %0, %1, %2" : "=v"(P0.w[1]) : "v"(s[0][2]), "v"(s[0][3])); \
        asm("v_cvt_pk_bf16_f32 %0, %1, %2" : "=v"(P0.w[2]) : "v"(s[1][0]), "v"(s[1][1])); \
        asm("v_cvt_pk_bf16_f32 %0, %1, %2" : "=v"(P0.w[3]) : "v"(s[1][2]), "v"(s[1][3])); \
        asm("v_cvt_pk_bf16_f32 %0, %1, %2" : "=v"(P1.w[0]) : "v"(s[2][0]), "v"(s[2][1])); \
        asm("v_cvt_pk_bf16_f32 %0, %1, %2" : "=v"(P1.w[1]) : "v"(s[2][2]), "v"(s[2][3])); \
        asm("v_cvt_pk_bf16_f32 %0, %1, %2" : "=v"(P1.w[2]) : "v"(s[3][0]), "v"(s[3][1])); \
        asm("v_cvt_pk_bf16_f32 %0, %1, %2" : "=v"(P1.w[3]) : "v"(s[3][2]), "v"(s[3][3])); \
        __builtin_amdgcn_s_setprio(1);                                        \
        _Pragma("unroll")                                                     \
        for (int dsub = 0; dsub < 4; ++dsub) {                                \
            const s16x8 vf0 = *(const s16x8*)(LB + cc + base0 + 16384 + dsub * 2048); \
            const s16x8 vf1 = *(const s16x8*)(LB + cc + base1 + 16384 + dsub * 2048); \
            O[dsub] = MFMA16(vf0, P0.v, O[dsub], 0, 0, 0);                    \
            O[dsub] = MFMA16(vf1, P1.v, O[dsub], 0, 0, 0);                    \
        }                                                                     \
        lacc = MFMA16(ones, P0.v, lacc, 0, 0, 0);                             \
        lacc = MFMA16(ones, P1.v, lacc, 0, 0, 0);                             \
        __builtin_amdgcn_s_setprio(0);                                        \
        asm volatile("s_waitcnt vmcnt(3)" ::: "memory");                      \
        __builtin_amdgcn_s_barrier();                                         \
        __builtin_amdgcn_sched_barrier(0);                                    \
        cc += BUFB; if (cc == 3 * BUFB) cc = 0;                               \
        cs += BUFB; if (cs == 3 * BUFB) cs = 0;                               \
    }

    int cc = 0, cs = 2 * BUFB;

    BIASLOAD(0, cBA, cBB)
    STAGE(0, 0)
    STAGE(1, BUFB)
    asm volatile("s_waitcnt vmcnt(3)" ::: "memory");
    __builtin_amdgcn_s_barrier();
    __builtin_amdgcn_sched_barrier(0);

#pragma unroll 1
    for (int it = 0; it < 32; it += 2) {
        ITER(it,     cBA, cBB, nBA, nBB)
        ITER(it + 1, nBA, nBB, cBA, cBB)
    }

    const float rl = 1.f / lacc[0];
    const int row = bb * 2048 + q;
    const int r128 = row & 127;
    const int xr = (r128 >> 1) & 3;
    unsigned short* __restrict__ ab = AOb + ((size_t)(row >> 7)) * 65536
                                    + r128 * 32 + (g & 1) * 4;
#pragma unroll
    for (int dsub = 0; dsub < 4; ++dsub) {
        const f32x4 o = O[dsub] * rl;
        const int ch = hh * 2 + (dsub >> 1);
        const int slot = ((dsub & 1) * 2 + (g >> 1)) ^ xr;
        u16x4 pk;
#pragma unroll
        for (int c = 0; c < 4; ++c) pk[c] = f2bf(o[c]);
        *(u16x4*)(ab + (size_t)ch * 4096 + slot * 8) = pk;
    }
#undef STAGE
#undef BIASLOAD
#undef UNPK
#undef ITER
}

// ---------------------------------------------------------------------------
// Kernel 4: MFMA epilogue GEMM AObf[8192,512] @ WO[512,384pad] -> out fp32.
// ---------------------------------------------------------------------------
__global__ __launch_bounds__(256) void epi_mfma_kernel(
    const unsigned short* __restrict__ AOb, const unsigned short* __restrict__ WOT,
    float* __restrict__ out)
{
    const int stile = blockIdx.x, jtile = blockIdx.y;
    const int tid = threadIdx.x, wv = tid >> 6, lane = tid & 63;
    const int li = lane & 15, g = lane >> 4;

    __shared__ __align__(16) char LBe[24576];   // 2 bufs x (A 4KB | W 8KB)

    const unsigned short* __restrict__ pA =
        AOb + (size_t)(stile >> 1) * 65536 + (stile & 1) * 2048 + tid * 8;
    const unsigned short* __restrict__ pW = WOT + (size_t)jtile * 65536 + tid * 8;

#define STAGEE(ch, bofs) {                                                    \
        char* dbA = LBe + (bofs) + wv * 1024;                                 \
        const size_t co = (size_t)(ch) * 4096;                                \
        gload16(pA + co,        dbA);                                         \
        gload16(pW + co,        dbA + 4096);                                  \
        gload16(pW + co + 2048, dbA + 8192);                                  \
    }

    int offA[4], offW[2];
#pragma unroll
    for (int ssub = 0; ssub < 4; ++ssub) {
        const int r = ssub * 16 + li;
        offA[ssub] = r * 64 + ((g ^ ((r >> 1) & 3)) << 4);
    }
#pragma unroll
    for (int jsub = 0; jsub < 2; ++jsub) {
        const int n = wv * 32 + jsub * 16 + li;
        offW[jsub] = 4096 + n * 64 + ((g ^ ((n >> 1) & 3)) << 4);
    }

    f32x4 acc[4][2];
#pragma unroll
    for (int i = 0; i < 4; ++i)
#pragma unroll
        for (int j = 0; j < 2; ++j) acc[i][j] = (f32x4){0.f, 0.f, 0.f, 0.f};

    STAGEE(0, 0)
    __syncthreads();

#pragma unroll 1
    for (int ch = 0; ch < 16; ++ch) {
        const int bofs = (ch & 1) * 12288;
        if (ch < 15) STAGEE(ch + 1, bofs ^ 12288)
        const char* bp = LBe + bofs;
        s16x8 ah[4], wh[2];
#pragma unroll
        for (int ssub = 0; ssub < 4; ++ssub)
            ah[ssub] = *(const s16x8*)(bp + offA[ssub]);
#pragma unroll
        for (int jsub = 0; jsub < 2; ++jsub)
            wh[jsub] = *(const s16x8*)(bp + offW[jsub]);
        __builtin_amdgcn_s_setprio(1);
#pragma unroll
        for (int ssub = 0; ssub < 4; ++ssub)
#pragma unroll
            for (int jsub = 0; jsub < 2; ++jsub)
                acc[ssub][jsub] = MFMA16(ah[ssub], wh[jsub], acc[ssub][jsub], 0, 0, 0);
        __builtin_amdgcn_s_setprio(0);
        __syncthreads();
    }
#undef STAGEE

    const int nbase = jtile * 128 + wv * 32 + li;
    const int rbase = stile * 64 + 4 * g;
#pragma unroll
    for (int jsub = 0; jsub < 2; ++jsub) {
        const int o = nbase + jsub * 16;
        if (o < HIDIN) {
#pragma unroll
            for (int ssub = 0; ssub < 4; ++ssub) {
                const f32x4 v = acc[ssub][jsub];
                const int r0 = rbase + ssub * 16;
#pragma unroll
                for (int r = 0; r < 4; ++r)
                    out[(size_t)(r0 + r) * HIDIN + o] = v[r];
            }
        }
    }
}

// ---------------------------------------------------------------------------
extern "C" void kernel_launch(void* const* d_in, const int* in_sizes, int n_in,
                              void* d_out, int out_size, void* d_ws, size_t ws_size,
                              hipStream_t stream)
{
    const float* en  = (const float*)d_in[0];
    const float* de  = (const float*)d_in[1];
    const int*   mask = (const int*)d_in[2];
    const float* WQ  = (const float*)d_in[3];
    const float* WK  = (const float*)d_in[4];
    const float* WV  = (const float*)d_in[5];
    const float* WO  = (const float*)d_in[6];
    float* out = (float*)d_out;

    unsigned short* ws2 = (unsigned short*)d_ws;
    unsigned short* Qh  = ws2 + OF_QH;
    unsigned short* Ql  = ws2 + OF_QL;
    unsigned short* KhT = ws2 + OF_KH;
    unsigned short* KlT = ws2 + OF_KL;
    unsigned short* VtT = ws2 + OF_VT;
    unsigned short* CA  = ws2 + OF_CA;
    unsigned short* CW  = ws2 + OF_CW;
    unsigned short* WOT = ws2 + OF_WOT;
    unsigned short* AOb = CA;                                 // aliases conv-A (dead after proj)
    unsigned int*  BiasT = (unsigned int*)(CA + 4194304);     // aliases conv-A tail

    convA_kernel<<<dim3(320, 2), 256, 0, stream>>>(de, en, CA);
    convW_kernel<<<dim3(672), 256, 0, stream>>>(WQ, WK, WV, WO, CW, WOT);
    proj_qk_kernel<<<dim3(512), 256, 0, stream>>>(CA, CW, Qh, Ql, KhT, KlT);
    proj_v_kernel<<<dim3(256), 256, 0, stream>>>(CA, CW, VtT);
    bias_kernel<<<dim3(256), 256, 0, stream>>>(mask, BiasT);
    attn_mfma_kernel<<<dim3(16, 32), 512, 0, stream>>>(Qh, Ql, KhT, KlT, VtT,
                                                       BiasT, AOb);
    epi_mfma_kernel<<<dim3(128, 3), 256, 0, stream>>>(AOb, WOT, out);
}

// Round 17
// 175.805 us; speedup vs baseline: 1.1706x; 1.0021x over previous
//
#include <hip/hip_runtime.h>
#include <hip/hip_bf16.h>
#include <math.h>

#define B_      4
#define SD_     2048
#define SE_     2048
#define HIDIN   300
#define HIDMID  512
#define NH      8
#define DH      64
#define ESZ     ((size_t)4194304)          // elems per [32][2048][64] tensor
#define BUFB    24576                       // bytes per attn LDS buffer (Kh+Kl+V)

typedef __attribute__((ext_vector_type(8))) short          s16x8;
typedef __attribute__((ext_vector_type(8))) unsigned short u16x8;
typedef __attribute__((ext_vector_type(4))) unsigned short u16x4;
typedef __attribute__((ext_vector_type(4))) float          f32x4;

#define MFMA16 __builtin_amdgcn_mfma_f32_16x16x32_bf16

// logit scale: (1/sqrt(300)) * log2(e)  -> softmax done in base-2
#define QSCALE  0.0832940411f
#define NEGL   -1.4426950e9f               // -1e9 * log2e
#define DEFER_THR 24.0f                    // defer-max threshold (base-2 units)

__device__ __forceinline__ unsigned short f2bf(float f) {
    unsigned int u = __float_as_uint(f);
    u += 0x7fffu + ((u >> 16) & 1u);          // RNE
    return (unsigned short)(u >> 16);
}
__device__ __forceinline__ float bf2f(unsigned short s) {
    return __uint_as_float((unsigned int)s << 16);
}
__device__ __forceinline__ void gload16(const void* g, void* l) {
    __builtin_amdgcn_global_load_lds(
        (const __attribute__((address_space(1))) void*)g,
        (__attribute__((address_space(3))) void*)l, 16, 0, 0);
}
// Raw v_exp_f32 (no OCML denormal fixup): inputs <= ~0; anything < -126
// underflows to 0, exactly what softmax wants (masked -1.4e9 -> 0, no NaN).
__device__ __forceinline__ float fexp2(float x) {
#if __has_builtin(__builtin_amdgcn_exp2f)
    return __builtin_amdgcn_exp2f(x);
#else
    return exp2f(x);
#endif
}

// ws ushort offsets
#define OF_QH   ((size_t)0)
#define OF_QL   (ESZ)
#define OF_KH   (2*ESZ)
#define OF_KL   (3*ESZ)
#define OF_VT   (4*ESZ)
#define OF_CA   (5*ESZ)                    // deH,deL,enH,enL (4 x 2621440)
#define OF_CW   (OF_CA + 10485760)         // WQh,WQl,WKh,WKl,WVh,WVl (6 x 163840)
#define OF_WOT  (OF_CW + 983040)           // 196608

// ---------------------------------------------------------------------------
// Kernel 0 (runs AFTER proj; lives in dead conv-A ws): mask (int32) ->
// packed-bf16-pair bias table {0, NEGL}. Pre-softmax additive bias keeps the
// running max masked-aware (numerically REQUIRED — see R12 NaN post-mortem).
// addr(u32) = ((((q>>4)*32 + tile)*4 + g)*16 + (q&15))*8, elem = sub*4+c,
// t = sub*16 + g*4 + c.
// ---------------------------------------------------------------------------
__global__ __launch_bounds__(256) void bias_kernel(const int* __restrict__ mask,
                                                   unsigned int* __restrict__ BiasT)
{
    const int idx = blockIdx.x * 256 + threadIdx.x;    // 65536 threads
    const int q = idx >> 5, tile = idx & 31;
    const int* __restrict__ mrow = mask + (size_t)q * SE_ + tile * 64;
    const unsigned int NEGB = (unsigned int)f2bf(NEGL);
    const int qblk = q >> 4, qlo = q & 15;
#pragma unroll
    for (int g = 0; g < 4; ++g) {
        unsigned int w[8];
#pragma unroll
        for (int sub = 0; sub < 4; ++sub) {
            const int4 mm = *(const int4*)(mrow + sub * 16 + g * 4);
            w[sub * 2]     = (mm.x ? NEGB : 0u) | ((mm.y ? NEGB : 0u) << 16);
            w[sub * 2 + 1] = (mm.z ? NEGB : 0u) | ((mm.w ? NEGB : 0u) << 16);
        }
        unsigned int* dst = BiasT +
            ((((size_t)qblk * 32 + tile) * 4 + g) * 16 + qlo) * 8;
        *(uint4*)dst       = make_uint4(w[0], w[1], w[2], w[3]);
        *(uint4*)(dst + 4) = make_uint4(w[4], w[5], w[6], w[7]);
    }
}

// ---------------------------------------------------------------------------
// Kernel 1a: de/en fp32 -> split bf16 hi/lo, tiled GEMM-A layout.
// ---------------------------------------------------------------------------
__global__ __launch_bounds__(256) void convA_kernel(
    const float* __restrict__ de, const float* __restrict__ en,
    unsigned short* __restrict__ CA)
{
    const int idx = blockIdx.x * 256 + threadIdx.x;    // 81920 per matrix
    const int mat = blockIdx.y;
    const float* __restrict__ A = mat ? en : de;
    unsigned short* __restrict__ H = CA + (size_t)mat * 5242880;
    unsigned short* __restrict__ L = H + 2621440;
    const int row = idx / 10, ch = idx - row * 10;
    float v[32];
    if (ch < 9) {
#pragma unroll
        for (int i = 0; i < 8; ++i) {
            const float4 f = *(const float4*)(A + (size_t)row * 300 + ch * 32 + i * 4);
            v[i*4+0] = f.x; v[i*4+1] = f.y; v[i*4+2] = f.z; v[i*4+3] = f.w;
        }
    } else {
#pragma unroll
        for (int i = 0; i < 32; ++i) {
            const int k = 288 + i;
            v[i] = (k < 300) ? A[(size_t)row * 300 + k] : 0.f;
        }
    }
    const int r128 = row & 127;
    const int xr = (r128 >> 1) & 3;
    const size_t tb = ((size_t)(row >> 7) * 10 + ch) * 4096 + r128 * 32;
#pragma unroll
    for (int sub = 0; sub < 4; ++sub) {
        const int slot = sub ^ xr;
        u16x8 hv, lv;
#pragma unroll
        for (int e = 0; e < 8; ++e) {
            const float f = v[sub * 8 + e];
            const unsigned short h = f2bf(f);
            hv[e] = h; lv[e] = f2bf(f - bf2f(h));
        }
        *(u16x8*)(H + tb + slot * 8) = hv;
        *(u16x8*)(L + tb + slot * 8) = lv;
    }
}

// ---------------------------------------------------------------------------
// Kernel 1b: WQ/WK -> split bf16 hi/lo transposed tiled (QSCALE folded into
// WQ); WV hi only; WO -> plain bf16 transposed tiled (n padded 300->384).
// ---------------------------------------------------------------------------
__global__ __launch_bounds__(256) void convW_kernel(
    const float* __restrict__ WQ, const float* __restrict__ WK,
    const float* __restrict__ WV, const float* __restrict__ WO,
    unsigned short* __restrict__ CW, unsigned short* __restrict__ WOT)
{
    const int idx = blockIdx.x * 256 + threadIdx.x;
    if (idx < 122880) {                       // QKV: which x k(320) x n4(128)
        const int which = idx / 40960;
        const int rem = idx - which * 40960;
        const int k = rem >> 7;
        const int n0 = (rem & 127) * 4;
        const float* __restrict__ W = which == 0 ? WQ : (which == 1 ? WK : WV);
        unsigned short* __restrict__ H = CW + (size_t)which * 327680;
        unsigned short* __restrict__ L = H + 163840;
        const float sc = (which == 0) ? QSCALE : 1.f;
        float4 w = make_float4(0.f, 0.f, 0.f, 0.f);
        if (k < 300) w = *(const float4*)(W + (size_t)k * 512 + n0);
        const float wv4[4] = {w.x * sc, w.y * sc, w.z * sc, w.w * sc};
        const int ch = k >> 5, kk = k & 31;
#pragma unroll
        for (int j = 0; j < 4; ++j) {
            const int n = n0 + j, ntile = n >> 7, nr = n & 127;
            const size_t o = ((size_t)(ntile * 10 + ch) * 128 + nr) * 32
                           + (((kk >> 3) ^ ((nr >> 1) & 3)) << 3) + (kk & 7);
            const unsigned short h = f2bf(wv4[j]);
            H[o] = h;
            if (which < 2) L[o] = f2bf(wv4[j] - bf2f(h));
        }
    } else {                                   // WO: k(512) x n4(96)
        const int idx2 = idx - 122880;
        const int k = idx2 / 96, n4 = idx2 - k * 96;
        const int n0 = n4 * 4;
        float4 w = make_float4(0.f, 0.f, 0.f, 0.f);
        if (n0 < 300) w = *(const float4*)(WO + (size_t)k * 300 + n0);
        const float wv4[4] = {w.x, w.y, w.z, w.w};
        const int ch = k >> 5, kk = k & 31;
#pragma unroll
        for (int j = 0; j < 4; ++j) {
            const int n = n0 + j, ntile = n >> 7, nr = n & 127;
            const size_t o = ((size_t)(ntile * 16 + ch) * 128 + nr) * 32
                           + (((kk >> 3) ^ ((nr >> 1) & 3)) << 3) + (kk & 7);
            WOT[o] = f2bf(wv4[j]);
        }
    }
}

// ---------------------------------------------------------------------------
// Kernel 2a: MFMA Q/K projection (3-term). 512 blocks = exactly 2/CU, one
// full dispatch wave. XCD swizzle keeps same-A-panel jtiles on one XCD.
// ---------------------------------------------------------------------------
__global__ __launch_bounds__(256) void proj_qk_kernel(
    const unsigned short* __restrict__ CA, const unsigned short* __restrict__ CW,
    unsigned short* __restrict__ Qh, unsigned short* __restrict__ Ql,
    unsigned short* __restrict__ KhT, unsigned short* __restrict__ KlT)
{
    const int lin = blockIdx.x;
    const int which = lin >> 8;                        // 0=Q, 1=K
    const int t = lin & 255;
    const int stile = (t & 7) | ((t >> 5) << 3);
    const int jtile = (t >> 3) & 3;
    const int tid = threadIdx.x, wv = tid >> 6, lane = tid & 63;
    const int li = lane & 15, g = lane >> 4;
    const int wr = wv >> 1, wc = wv & 1;

    __shared__ __align__(16) char LBp[65536];   // 2 bufs x (Ah|Al|Wh|Wl) x 8KB

    const unsigned short* __restrict__ pAh =
        CA + (size_t)which * 5242880 + (size_t)stile * 40960 + tid * 8;
    const unsigned short* __restrict__ pAl = pAh + 2621440;
    const unsigned short* __restrict__ pWh =
        CW + (size_t)which * 327680 + (size_t)jtile * 40960 + tid * 8;
    const unsigned short* __restrict__ pWl = pWh + 163840;

#define STAGEP(ch, bofs) {                                                    \
        char* db = LBp + (bofs) + wv * 1024;                                  \
        const size_t co = (size_t)(ch) * 4096;                                \
        gload16(pAh + co,        db);                                         \
        gload16(pAh + co + 2048, db + 4096);                                  \
        gload16(pAl + co,        db + 8192);                                  \
        gload16(pAl + co + 2048, db + 12288);                                 \
        gload16(pWh + co,        db + 16384);                                 \
        gload16(pWh + co + 2048, db + 20480);                                 \
        gload16(pWl + co,        db + 24576);                                 \
        gload16(pWl + co + 2048, db + 28672);                                 \
    }

    int offA[4], offW[4];
#pragma unroll
    for (int ssub = 0; ssub < 4; ++ssub) {
        const int r = wr * 64 + ssub * 16 + li;
        offA[ssub] = r * 64 + ((g ^ ((r >> 1) & 3)) << 4);
    }
#pragma unroll
    for (int jsub = 0; jsub < 4; ++jsub) {
        const int n = wc * 64 + jsub * 16 + li;
        offW[jsub] = n * 64 + ((g ^ ((n >> 1) & 3)) << 4);
    }

    f32x4 acc[4][4];
#pragma unroll
    for (int i = 0; i < 4; ++i)
#pragma unroll
        for (int j = 0; j < 4; ++j) acc[i][j] = (f32x4){0.f, 0.f, 0.f, 0.f};

    STAGEP(0, 0)
    __syncthreads();

#pragma unroll 1
    for (int ch = 0; ch < 10; ++ch) {
        const int bofs = (ch & 1) * 32768;
        if (ch < 9) STAGEP(ch + 1, bofs ^ 32768)
        const char* bp = LBp + bofs;
        s16x8 ah[4], al[4], wh[4], wl[4];
#pragma unroll
        for (int ssub = 0; ssub < 4; ++ssub) {
            ah[ssub] = *(const s16x8*)(bp + offA[ssub]);
            al[ssub] = *(const s16x8*)(bp + 8192 + offA[ssub]);
        }
#pragma unroll
        for (int jsub = 0; jsub < 4; ++jsub) {
            wh[jsub] = *(const s16x8*)(bp + 16384 + offW[jsub]);
            wl[jsub] = *(const s16x8*)(bp + 24576 + offW[jsub]);
        }
        __builtin_amdgcn_s_setprio(1);
#pragma unroll
        for (int ssub = 0; ssub < 4; ++ssub)
#pragma unroll
            for (int jsub = 0; jsub < 4; ++jsub) {
                acc[ssub][jsub] = MFMA16(ah[ssub], wh[jsub], acc[ssub][jsub], 0, 0, 0);
                acc[ssub][jsub] = MFMA16(ah[ssub], wl[jsub], acc[ssub][jsub], 0, 0, 0);
                acc[ssub][jsub] = MFMA16(al[ssub], wh[jsub], acc[ssub][jsub], 0, 0, 0);
            }
        __builtin_amdgcn_s_setprio(0);
        __syncthreads();
    }
#undef STAGEP

    const int jgbase = jtile * 128 + wc * 64 + li;
    const int sbase0 = stile * 128 + wr * 64 + 4 * g;
#pragma unroll
    for (int jsub = 0; jsub < 4; ++jsub) {
        const int jgg = jgbase + jsub * 16;
        const int d = jgg >> 3, hh = jgg & 7;
#pragma unroll
        for (int ssub = 0; ssub < 4; ++ssub) {
            const f32x4 v = acc[ssub][jsub];
            const int sg0 = sbase0 + ssub * 16;
            const int bbv = sg0 >> 11;
            const int bhn = bbv * 8 + hh;
            const int sl0 = sg0 & 2047;
            if (which == 0) {
                const size_t o = ((size_t)bhn * 2048 + sl0) * 64 + d;
#pragma unroll
                for (int r = 0; r < 4; ++r) {
                    const float val = v[r];
                    const unsigned short hi = f2bf(val);
                    Qh[o + r * 64] = hi;
                    Ql[o + r * 64] = f2bf(val - bf2f(hi));
                }
            } else {
                const int tile = sl0 >> 6, tt0 = sl0 & 63;
                const size_t tb = ((size_t)(bhn * 32 + tile)) << 12;
#pragma unroll
                for (int r = 0; r < 4; ++r) {
                    const int tt = tt0 + r;
                    const size_t o = tb + tt * 64 + (((d >> 3) ^ (tt & 7)) << 3) + (d & 7);
                    const float val = v[r];
                    const unsigned short hi = f2bf(val);
                    KhT[o] = hi;
                    KlT[o] = f2bf(val - bf2f(hi));
                }
            }
        }
    }
}

// ---------------------------------------------------------------------------
// Kernel 2b: MFMA V projection (1-term, Ah*Wh). 256 blocks, 32 KB LDS.
// ---------------------------------------------------------------------------
__global__ __launch_bounds__(256) void proj_v_kernel(
    const unsigned short* __restrict__ CA, const unsigned short* __restrict__ CW,
    unsigned short* __restrict__ VtT)
{
    const int t = blockIdx.x;
    const int stile = (t & 7) | ((t >> 5) << 3);
    const int jtile = (t >> 3) & 3;
    const int tid = threadIdx.x, wv = tid >> 6, lane = tid & 63;
    const int li = lane & 15, g = lane >> 4;
    const int wr = wv >> 1, wc = wv & 1;

    __shared__ __align__(16) char LBv[32768];   // 2 bufs x (Ah|Wh) x 8KB

    const unsigned short* __restrict__ pAh =
        CA + (size_t)1 * 5242880 + (size_t)stile * 40960 + tid * 8;   // en hi
    const unsigned short* __restrict__ pWh =
        CW + (size_t)2 * 327680 + (size_t)jtile * 40960 + tid * 8;    // WV hi

#define STAGEV(ch, bofs) {                                                    \
        char* db = LBv + (bofs) + wv * 1024;                                  \
        const size_t co = (size_t)(ch) * 4096;                                \
        gload16(pAh + co,        db);                                         \
        gload16(pAh + co + 2048, db + 4096);                                  \
        gload16(pWh + co,        db + 8192);                                  \
        gload16(pWh + co + 2048, db + 12288);                                 \
    }

    int offA[4], offW[4];
#pragma unroll
    for (int ssub = 0; ssub < 4; ++ssub) {
        const int r = wr * 64 + ssub * 16 + li;
        offA[ssub] = r * 64 + ((g ^ ((r >> 1) & 3)) << 4);
    }
#pragma unroll
    for (int jsub = 0; jsub < 4; ++jsub) {
        const int n = wc * 64 + jsub * 16 + li;
        offW[jsub] = 8192 + n * 64 + ((g ^ ((n >> 1) & 3)) << 4);
    }

    f32x4 acc[4][4];
#pragma unroll
    for (int i = 0; i < 4; ++i)
#pragma unroll
        for (int j = 0; j < 4; ++j) acc[i][j] = (f32x4){0.f, 0.f, 0.f, 0.f};

    STAGEV(0, 0)
    __syncthreads();

#pragma unroll 1
    for (int ch = 0; ch < 10; ++ch) {
        const int bofs = (ch & 1) * 16384;
        if (ch < 9) STAGEV(ch + 1, bofs ^ 16384)
        const char* bp = LBv + bofs;
        s16x8 ah[4], wh[4];
#pragma unroll
        for (int ssub = 0; ssub < 4; ++ssub)
            ah[ssub] = *(const s16x8*)(bp + offA[ssub]);
#pragma unroll
        for (int jsub = 0; jsub < 4; ++jsub)
            wh[jsub] = *(const s16x8*)(bp + offW[jsub]);
        __builtin_amdgcn_s_setprio(1);
#pragma unroll
        for (int ssub = 0; ssub < 4; ++ssub)
#pragma unroll
            for (int jsub = 0; jsub < 4; ++jsub)
                acc[ssub][jsub] = MFMA16(ah[ssub], wh[jsub], acc[ssub][jsub], 0, 0, 0);
        __builtin_amdgcn_s_setprio(0);
        __syncthreads();
    }
#undef STAGEV

    const int jgbase = jtile * 128 + wc * 64 + li;
    const int sbase0 = stile * 128 + wr * 64 + 4 * g;
#pragma unroll
    for (int jsub = 0; jsub < 4; ++jsub) {
        const int jgg = jgbase + jsub * 16;
        const int d = jgg >> 3, hh = jgg & 7;
#pragma unroll
        for (int ssub = 0; ssub < 4; ++ssub) {
            const f32x4 v = acc[ssub][jsub];
            const int sg0 = sbase0 + ssub * 16;
            const int bbv = sg0 >> 11;
            const int bhn = bbv * 8 + hh;
            const int sl0 = sg0 & 2047;
            const int tile = sl0 >> 6, tin0 = sl0 & 63;
            const size_t tb = ((size_t)(bhn * 32 + tile)) << 12;
            const int blk = tin0 >> 5, gg2 = (tin0 >> 2) & 3, half = (tin0 >> 4) & 1;
            const size_t o = tb + (size_t)d * 64
                           + ((((blk << 2) | gg2) ^ (d & 7)) << 3) + half * 4;
            u16x4 pk;
#pragma unroll
            for (int r = 0; r < 4; ++r) pk[r] = f2bf(v[r]);
            *(u16x4*)(VtT + o) = pk;
        }
    }
}

// ---------------------------------------------------------------------------
// Kernel 3: MFMA flash attention (R14-verified). 3-term S, 8 waves x 16 q,
// 3-buffer ring + counted vmcnt(3), setprio, XCD swizzle, defer-max,
// bf16-pair bias table (pre-softmax, masked-aware max), ones-l, raw exp2.
// ---------------------------------------------------------------------------
__global__ __launch_bounds__(512, 4) void attn_mfma_kernel(
    const unsigned short* __restrict__ Qh, const unsigned short* __restrict__ Ql,
    const unsigned short* __restrict__ KhT, const unsigned short* __restrict__ KlT,
    const unsigned short* __restrict__ VtT, const unsigned int* __restrict__ BiasT,
    unsigned short* __restrict__ AOb)
{
    const int lin = blockIdx.x + 16 * blockIdx.y;
    const int qt = (lin >> 3) & 15;
    const int bh = (lin & 7) + ((lin >> 7) << 3);
    const int bb = bh >> 3, hh = bh & 7;
    const int tid = threadIdx.x;
    const int wv = tid >> 6, lane = tid & 63;
    const int g = lane >> 4, li = lane & 15;
    const int q = qt * 128 + wv * 16 + li;

    __shared__ __align__(16) char LB[3 * BUFB];       // 72 KB

    const size_t qoff = ((size_t)bh * SD_ + q) * DH + 8 * g;
    const s16x8 qh0 = *(const s16x8*)(Qh + qoff);
    const s16x8 qh1 = *(const s16x8*)(Qh + qoff + 32);
    const s16x8 ql0 = *(const s16x8*)(Ql + qoff);
    const s16x8 ql1 = *(const s16x8*)(Ql + qoff + 32);

    const unsigned short* __restrict__ sKh = KhT + ((size_t)bh << 17) + tid * 8;
    const unsigned short* __restrict__ sKl = KlT + ((size_t)bh << 17) + tid * 8;
    const unsigned short* __restrict__ sVt = VtT + ((size_t)bh << 17) + tid * 8;

    const int base0 = li * 128 + ((g ^ (li & 7)) << 4);
    const int base1 = li * 128 + (((4 + g) ^ (li & 7)) << 4);

    // bias table base (u32 units); per-tile stride = 512 u32
    const size_t bbase = (size_t)(qt * 8 + wv) * 16384 + g * 128 + li * 8;

#define BIASLOAD(T, RA, RB) {                                                 \
        const uint4* p = (const uint4*)(BiasT + bbase + (size_t)(T) * 512);   \
        RA = p[0]; RB = p[1];                                                 \
    }
#define STAGE(tile, boff)                                                     \
    {                                                                         \
        char* db = LB + (boff) + wv * 1024;                                   \
        const size_t toff = (size_t)(tile) << 12;                             \
        gload16(sKh + toff, db);                                              \
        gload16(sKl + toff, db + 8192);                                       \
        gload16(sVt + toff, db + 16384);                                      \
    }

    float m = -INFINITY;
    f32x4 O[4], lacc;
#pragma unroll
    for (int i = 0; i < 4; ++i) O[i] = (f32x4){0.f, 0.f, 0.f, 0.f};
    lacc = (f32x4){0.f, 0.f, 0.f, 0.f};

    s16x8 ones;
#pragma unroll
    for (int i = 0; i < 8; ++i) ones[i] = (short)0x3F80;

    uint4 cBA, cBB, nBA, nBB;

#define UNPK(W, S, sub, cbase)                                                \
        S[sub][cbase]     = __uint_as_float((W) << 16);                       \
        S[sub][cbase + 1] = __uint_as_float((W) & 0xFFFF0000u);

#define ITER(IT, CBA_, CBB_, NBA_, NBB_)                                      \
    {                                                                         \
        BIASLOAD(((IT) + 1) & 31, NBA_, NBB_)                                 \
        STAGE(((IT) + 2) & 31, cs)                                            \
        f32x4 s[4];                                                           \
        UNPK(CBA_.x, s, 0, 0) UNPK(CBA_.y, s, 0, 2)                           \
        UNPK(CBA_.z, s, 1, 0) UNPK(CBA_.w, s, 1, 2)                           \
        UNPK(CBB_.x, s, 2, 0) UNPK(CBB_.y, s, 2, 2)                           \
        UNPK(CBB_.z, s, 3, 0) UNPK(CBB_.w, s, 3, 2)                           \
        __builtin_amdgcn_s_setprio(1);                                        \
        _Pragma("unroll")                                                     \
        for (int sub = 0; sub < 4; ++sub) {                                   \
            const s16x8 kh0 = *(const s16x8*)(LB + cc + base0 + sub * 2048);  \
            const s16x8 kh1 = *(const s16x8*)(LB + cc + base1 + sub * 2048);  \
            const s16x8 kl0 = *(const s16x8*)(LB + cc + base0 + 8192 + sub * 2048); \
            const s16x8 kl1 = *(const s16x8*)(LB + cc + base1 + 8192 + sub * 2048); \
            s[sub] = MFMA16(kh0, qh0, s[sub], 0, 0, 0);                       \
            s[sub] = MFMA16(kh0, ql0, s[sub], 0, 0, 0);                       \
            s[sub] = MFMA16(kl0, qh0, s[sub], 0, 0, 0);                       \
            s[sub] = MFMA16(kh1, qh1, s[sub], 0, 0, 0);                       \
            s[sub] = MFMA16(kh1, ql1, s[sub], 0, 0, 0);                       \
            s[sub] = MFMA16(kl1, qh1, s[sub], 0, 0, 0);                       \
        }                                                                     \
        __builtin_amdgcn_s_setprio(0);                                        \
        float x0 = fmaxf(fmaxf(s[0][0], s[0][1]), s[0][2]);                   \
        float x1 = fmaxf(fmaxf(s[0][3], s[1][0]), s[1][1]);                   \
        float x2 = fmaxf(fmaxf(s[1][2], s[1][3]), s[2][0]);                   \
        float x3 = fmaxf(fmaxf(s[2][1], s[2][2]), s[2][3]);                   \
        float x4 = fmaxf(fmaxf(s[3][0], s[3][1]), s[3][2]);                   \
        float tmax = fmaxf(fmaxf(fmaxf(x0, x1), fmaxf(x2, x3)),               \
                           fmaxf(x4, s[3][3]));                               \
        if (!__all(tmax <= m + DEFER_THR)) {                                  \
            float r = fmaxf(tmax, __shfl_xor(tmax, 16));                      \
            r = fmaxf(r, __shfl_xor(r, 32));                                  \
            const float mn  = fmaxf(m, r);                                    \
            const float scl = fexp2(m - mn);                                  \
            m = mn;                                                           \
            _Pragma("unroll")                                                 \
            for (int i = 0; i < 4; ++i) O[i] *= scl;                          \
            lacc *= scl;                                                      \
        }                                                                     \
        _Pragma("unroll")                                                     \
        for (int sub = 0; sub < 4; ++sub)                                     \
            _Pragma("unroll")                                                 \
            for (int c = 0; c < 4; ++c)                                       \
                s[sub][c] = fexp2(s[sub][c] - m);                             \
        union { s16x8 v; unsigned int w[4]; } P0, P1;                         \
        asm("v_cvt_pk_bf16_f32 %0, %1, %2" : "=v"(P0.w[0]) : "v"(s[0][0]), "v"(s[0][1])); \
        asm("v_cvt_pk_bf16_f32 %0, %1, %2" : "=v"(P0.w[1]) : "v"(s[0][2]), "v"(s[0][3])); \
        asm("v_cvt_pk_bf16_f32 %0, %1, %2" : "=v"(P0.w[2]) : "v"(s[1][0]), "v"(s[1][1])); \
        asm("v_cvt_pk_bf16_f32 %0, %1, %2" : "=v"(P0.w[3]) : "v"(s[1][2]), "v"(s[1][3])); \
        asm("v_cvt_pk_bf16_f32 %0, %1, %2" : "=v"(P1.w[0]) : "v"(s[2][0]), "v"(s[2][1])); \
        asm("v_cvt_pk_bf16_f32 %0, %1, %2" : "=v"(P1.w[1]) : "v"(s[2][2]), "v"(s[2][3])); \
        asm("v_cvt_pk_bf16_f32 %0, %1, %2" : "=v"(P1.w[2]) : "v"(s[3][0]), "v"(s[3][1])); \
        asm("v_cvt_pk_bf16_f32 %0, %1, %2" : "=v"(P1.w[3]) : "v"(s[3][2]), "v"(s[3][3])); \
        __builtin_amdgcn_s_setprio(1);                                        \
        _Pragma("unroll")                                                     \
        for (int dsub = 0; dsub < 4; ++dsub) {                                \
            const s16x8 vf0 = *(const s16x8*)(LB + cc + base0 + 16384 + dsub * 2048); \
            const s16x8 vf1 = *(const s16x8*)(LB + cc + base1 + 16384 + dsub * 2048); \
            O[dsub] = MFMA16(vf0, P0.v, O[dsub], 0, 0, 0);                    \
            O[dsub] = MFMA16(vf1, P1.v, O[dsub], 0, 0, 0);                    \
        }                                                                     \
        lacc = MFMA16(ones, P0.v, lacc, 0, 0, 0);                             \
        lacc = MFMA16(ones, P1.v, lacc, 0, 0, 0);                             \
        __builtin_amdgcn_s_setprio(0);                                        \
        asm volatile("s_waitcnt vmcnt(3)" ::: "memory");                      \
        __builtin_amdgcn_s_barrier();                                         \
        __builtin_amdgcn_sched_barrier(0);                                    \
        cc += BUFB; if (cc == 3 * BUFB) cc = 0;                               \
        cs += BUFB; if (cs == 3 * BUFB) cs = 0;                               \
    }

    int cc = 0, cs = 2 * BUFB;

    BIASLOAD(0, cBA, cBB)
    STAGE(0, 0)
    STAGE(1, BUFB)
    asm volatile("s_waitcnt vmcnt(3)" ::: "memory");
    __builtin_amdgcn_s_barrier();
    __builtin_amdgcn_sched_barrier(0);

#pragma unroll 1
    for (int it = 0; it < 32; it += 2) {
        ITER(it,     cBA, cBB, nBA, nBB)
        ITER(it + 1, nBA, nBB, cBA, cBB)
    }

    const float rl = 1.f / lacc[0];
    const int row = bb * 2048 + q;
    const int r128 = row & 127;
    const int xr = (r128 >> 1) & 3;
    unsigned short* __restrict__ ab = AOb + ((size_t)(row >> 7)) * 65536
                                    + r128 * 32 + (g & 1) * 4;
#pragma unroll
    for (int dsub = 0; dsub < 4; ++dsub) {
        const f32x4 o = O[dsub] * rl;
        const int ch = hh * 2 + (dsub >> 1);
        const int slot = ((dsub & 1) * 2 + (g >> 1)) ^ xr;
        u16x4 pk;
#pragma unroll
        for (int c = 0; c < 4; ++c) pk[c] = f2bf(o[c]);
        *(u16x4*)(ab + (size_t)ch * 4096 + slot * 8) = pk;
    }
#undef STAGE
#undef BIASLOAD
#undef UNPK
#undef ITER
}

// ---------------------------------------------------------------------------
// Kernel 4: MFMA epilogue GEMM AObf[8192,512] @ WO[512,384pad] -> out fp32.
// ---------------------------------------------------------------------------
__global__ __launch_bounds__(256) void epi_mfma_kernel(
    const unsigned short* __restrict__ AOb, const unsigned short* __restrict__ WOT,
    float* __restrict__ out)
{
    const int stile = blockIdx.x, jtile = blockIdx.y;
    const int tid = threadIdx.x, wv = tid >> 6, lane = tid & 63;
    const int li = lane & 15, g = lane >> 4;

    __shared__ __align__(16) char LBe[24576];   // 2 bufs x (A 4KB | W 8KB)

    const unsigned short* __restrict__ pA =
        AOb + (size_t)(stile >> 1) * 65536 + (stile & 1) * 2048 + tid * 8;
    const unsigned short* __restrict__ pW = WOT + (size_t)jtile * 65536 + tid * 8;

#define STAGEE(ch, bofs) {                                                    \
        char* dbA = LBe + (bofs) + wv * 1024;                                 \
        const size_t co = (size_t)(ch) * 4096;                                \
        gload16(pA + co,        dbA);                                         \
        gload16(pW + co,        dbA + 4096);                                  \
        gload16(pW + co + 2048, dbA + 8192);                                  \
    }

    int offA[4], offW[2];
#pragma unroll
    for (int ssub = 0; ssub < 4; ++ssub) {
        const int r = ssub * 16 + li;
        offA[ssub] = r * 64 + ((g ^ ((r >> 1) & 3)) << 4);
    }
#pragma unroll
    for (int jsub = 0; jsub < 2; ++jsub) {
        const int n = wv * 32 + jsub * 16 + li;
        offW[jsub] = 4096 + n * 64 + ((g ^ ((n >> 1) & 3)) << 4);
    }

    f32x4 acc[4][2];
#pragma unroll
    for (int i = 0; i < 4; ++i)
#pragma unroll
        for (int j = 0; j < 2; ++j) acc[i][j] = (f32x4){0.f, 0.f, 0.f, 0.f};

    STAGEE(0, 0)
    __syncthreads();

#pragma unroll 1
    for (int ch = 0; ch < 16; ++ch) {
        const int bofs = (ch & 1) * 12288;
        if (ch < 15) STAGEE(ch + 1, bofs ^ 12288)
        const char* bp = LBe + bofs;
        s16x8 ah[4], wh[2];
#pragma unroll
        for (int ssub = 0; ssub < 4; ++ssub)
            ah[ssub] = *(const s16x8*)(bp + offA[ssub]);
#pragma unroll
        for (int jsub = 0; jsub < 2; ++jsub)
            wh[jsub] = *(const s16x8*)(bp + offW[jsub]);
        __builtin_amdgcn_s_setprio(1);
#pragma unroll
        for (int ssub = 0; ssub < 4; ++ssub)
#pragma unroll
            for (int jsub = 0; jsub < 2; ++jsub)
                acc[ssub][jsub] = MFMA16(ah[ssub], wh[jsub], acc[ssub][jsub], 0, 0, 0);
        __builtin_amdgcn_s_setprio(0);
        __syncthreads();
    }
#undef STAGEE

    const int nbase = jtile * 128 + wv * 32 + li;
    const int rbase = stile * 64 + 4 * g;
#pragma unroll
    for (int jsub = 0; jsub < 2; ++jsub) {
        const int o = nbase + jsub * 16;
        if (o < HIDIN) {
#pragma unroll
            for (int ssub = 0; ssub < 4; ++ssub) {
                const f32x4 v = acc[ssub][jsub];
                const int r0 = rbase + ssub * 16;
#pragma unroll
                for (int r = 0; r < 4; ++r)
                    out[(size_t)(r0 + r) * HIDIN + o] = v[r];
            }
        }
    }
}

// ---------------------------------------------------------------------------
extern "C" void kernel_launch(void* const* d_in, const int* in_sizes, int n_in,
                              void* d_out, int out_size, void* d_ws, size_t ws_size,
                              hipStream_t stream)
{
    const float* en  = (const float*)d_in[0];
    const float* de  = (const float*)d_in[1];
    const int*   mask = (const int*)d_in[2];
    const float* WQ  = (const float*)d_in[3];
    const float* WK  = (const float*)d_in[4];
    const float* WV  = (const float*)d_in[5];
    const float* WO  = (const float*)d_in[6];
    float* out = (float*)d_out;

    unsigned short* ws2 = (unsigned short*)d_ws;
    unsigned short* Qh  = ws2 + OF_QH;
    unsigned short* Ql  = ws2 + OF_QL;
    unsigned short* KhT = ws2 + OF_KH;
    unsigned short* KlT = ws2 + OF_KL;
    unsigned short* VtT = ws2 + OF_VT;
    unsigned short* CA  = ws2 + OF_CA;
    unsigned short* CW  = ws2 + OF_CW;
    unsigned short* WOT = ws2 + OF_WOT;
    unsigned short* AOb = CA;                                 // aliases conv-A (dead after proj)
    unsigned int*  BiasT = (unsigned int*)(CA + 4194304);     // aliases conv-A tail

    convA_kernel<<<dim3(320, 2), 256, 0, stream>>>(de, en, CA);
    convW_kernel<<<dim3(672), 256, 0, stream>>>(WQ, WK, WV, WO, CW, WOT);
    proj_qk_kernel<<<dim3(512), 256, 0, stream>>>(CA, CW, Qh, Ql, KhT, KlT);
    proj_v_kernel<<<dim3(256), 256, 0, stream>>>(CA, CW, VtT);
    bias_kernel<<<dim3(256), 256, 0, stream>>>(mask, BiasT);
    attn_mfma_kernel<<<dim3(16, 32), 512, 0, stream>>>(Qh, Ql, KhT, KlT, VtT,
                                                       BiasT, AOb);
    epi_mfma_kernel<<<dim3(128, 3), 256, 0, stream>>>(AOb, WOT, out);
}